// Round 1
// baseline (575.162 us; speedup 1.0000x reference)
//
#include <hip/hip_runtime.h>
#include <hip/hip_bf16.h>
#include <math.h>

#define SEQL 2048
#define NB 4
#define DMm 256
#define DIi 512
#define DSs 32
#define NHH 8
#define HDD 64
#define CDD 576
#define ZXD 1096
#define ZXT 2192
#define NLAY 2
#define QC 64
#define NCH 32
#define RT 8192
#define EPSV 1e-5f

typedef __hip_bfloat16 bf16_t;
using short8 = __attribute__((ext_vector_type(8))) short;
using f32x4  = __attribute__((ext_vector_type(4))) float;

__device__ __forceinline__ int torig(int d, int c, int s) {
  int v = c * QC + s;
  return d ? (SEQL - 1 - v) : v;
}

__device__ __forceinline__ int is_masked(const void* mask, const int* mflag, int r) {
  return (*mflag) ? (int)(((const unsigned char*)mask)[r] != 0)
                  : (int)(((const int*)mask)[r] != 0);
}

// mask dtype detection: int32 {0,1} has all bytes at pos%4!=0 equal to 0;
// bool8 has ~half nonzero. Reading RT bytes is in-bounds for both layouts.
__global__ void detect_mask(const unsigned char* __restrict__ m, int* __restrict__ flag) {
  __shared__ int any;
  if (threadIdx.x == 0) any = 0;
  __syncthreads();
  int a = 0;
  for (int i = threadIdx.x; i < RT; i += blockDim.x)
    if ((i & 3) && m[i]) a = 1;
  if (a) atomicOr(&any, 1);
  __syncthreads();
  if (threadIdx.x == 0) *flag = any;
}

__global__ void cvt_weights(const float* __restrict__ in_w, const float* __restrict__ out_w,
                            bf16_t* __restrict__ inw_bf, bf16_t* __restrict__ wcat_bf) {
  const int n1 = NLAY * ZXT * DMm;
  const int n2 = NLAY * DMm * 1024;
  for (int idx = blockIdx.x * blockDim.x + threadIdx.x; idx < n1 + n2; idx += gridDim.x * blockDim.x) {
    if (idx < n1) {
      inw_bf[idx] = __float2bfloat16(in_w[idx]);   // [l][dir*1096+e][k] == source flat layout
    } else {
      int j = idx - n1;                            // wcat: [l][d(256)][k(1024)], k = dir*512+e
      int l = j / (DMm * 1024);
      int rem = j % (DMm * 1024);
      int dd = rem >> 10, k = rem & 1023;
      int dir = k >> 9, e = k & 511;
      wcat_bf[j] = __float2bfloat16(out_w[((size_t)((l * 2 + dir) * DMm) + dd) * DIi + e]);
    }
  }
}

__global__ void ln_kernel(const float* __restrict__ x, bf16_t* __restrict__ h,
                          const float* __restrict__ lnw, const float* __restrict__ lnb) {
  int r = blockIdx.x, lane = threadIdx.x;   // 64 threads, 4 cols each
  float4 v = ((const float4*)(x + (size_t)r * DMm))[lane];
  float s = v.x + v.y + v.z + v.w;
  #pragma unroll
  for (int o = 32; o; o >>= 1) s += __shfl_xor(s, o);
  float mu = s * (1.f / DMm);
  float d0 = v.x - mu, d1 = v.y - mu, d2 = v.z - mu, d3 = v.w - mu;
  float q = d0*d0 + d1*d1 + d2*d2 + d3*d3;
  #pragma unroll
  for (int o = 32; o; o >>= 1) q += __shfl_xor(q, o);
  float rstd = rsqrtf(q * (1.f / DMm) + EPSV);
  float4 w  = ((const float4*)lnw)[lane];
  float4 bb = ((const float4*)lnb)[lane];
  union { bf16_t o4[4]; uint2 u; } out;
  out.o4[0] = __float2bfloat16(d0 * rstd * w.x + bb.x);
  out.o4[1] = __float2bfloat16(d1 * rstd * w.y + bb.y);
  out.o4[2] = __float2bfloat16(d2 * rstd * w.z + bb.z);
  out.o4[3] = __float2bfloat16(d3 * rstd * w.w + bb.w);
  ((uint2*)(h + (size_t)r * DMm))[lane] = out.u;
}

__global__ void final_ln(const float* __restrict__ x, const void* __restrict__ mask,
                         const int* __restrict__ mflag,
                         const float* __restrict__ lnw, const float* __restrict__ lnb,
                         float* __restrict__ out) {
  int r = blockIdx.x, lane = threadIdx.x;
  float4 v = ((const float4*)(x + (size_t)r * DMm))[lane];
  float s = v.x + v.y + v.z + v.w;
  #pragma unroll
  for (int o = 32; o; o >>= 1) s += __shfl_xor(s, o);
  float mu = s * (1.f / DMm);
  float d0 = v.x - mu, d1 = v.y - mu, d2 = v.z - mu, d3 = v.w - mu;
  float q = d0*d0 + d1*d1 + d2*d2 + d3*d3;
  #pragma unroll
  for (int o = 32; o; o >>= 1) q += __shfl_xor(q, o);
  float rstd = rsqrtf(q * (1.f / DMm) + EPSV);
  float4 w  = ((const float4*)lnw)[lane];
  float4 bb = ((const float4*)lnb)[lane];
  float4 o4;
  if (is_masked(mask, mflag, r)) { o4.x = o4.y = o4.z = o4.w = 0.f; }
  else {
    o4.x = d0 * rstd * w.x + bb.x; o4.y = d1 * rstd * w.y + bb.y;
    o4.z = d2 * rstd * w.z + bb.z; o4.w = d3 * rstd * w.w + bb.w;
  }
  ((float4*)(out + (size_t)r * DMm))[lane] = o4;
}

// C = A(MxK) * Bw(NxK)^T ; bf16 inputs, fp32 out. EPI=0: store. EPI=1: masked +=.
template<int EPI>
__global__ __launch_bounds__(256) void gemm_k(const bf16_t* __restrict__ A, const bf16_t* __restrict__ Bw,
    float* __restrict__ C, int M, int N, int K, int ldc,
    const void* __restrict__ mask, const int* __restrict__ mflag) {
  __shared__ bf16_t As[64][40];   // pad 32->40 to spread banks
  __shared__ bf16_t Bs[64][40];
  int n0 = blockIdx.x * 64, m0 = blockIdx.y * 64;
  int tid = threadIdx.x, lane = tid & 63, wid = tid >> 6;
  f32x4 acc[4] = {};
  int sr = tid >> 2, sk = (tid & 3) * 8;
  for (int k0 = 0; k0 < K; k0 += 32) {
    short8 av = *(const short8*)(A + (size_t)(m0 + sr) * K + k0 + sk);
    *(short8*)&As[sr][sk] = av;
    int bn = n0 + sr;
    short8 bv = {0,0,0,0,0,0,0,0};
    if (bn < N) bv = *(const short8*)(Bw + (size_t)bn * K + k0 + sk);
    *(short8*)&Bs[sr][sk] = bv;
    __syncthreads();
    short8 af = *(const short8*)&As[wid * 16 + (lane & 15)][(lane >> 4) * 8];
    #pragma unroll
    for (int nt = 0; nt < 4; nt++) {
      short8 bf = *(const short8*)&Bs[nt * 16 + (lane & 15)][(lane >> 4) * 8];
      acc[nt] = __builtin_amdgcn_mfma_f32_16x16x32_bf16(af, bf, acc[nt], 0, 0, 0);
    }
    __syncthreads();
  }
  #pragma unroll
  for (int nt = 0; nt < 4; nt++) {
    int col = n0 + nt * 16 + (lane & 15);
    if (col < N) {
      #pragma unroll
      for (int j = 0; j < 4; j++) {
        int row = m0 + wid * 16 + (lane >> 4) * 4 + j;
        if (EPI == 0) C[(size_t)row * ldc + col] = acc[nt][j];
        else if (!is_masked(mask, mflag, row)) C[(size_t)row * ldc + col] += acc[nt][j];
      }
    }
  }
}

// depthwise causal conv (dir-aware) + silu, and dt/dt*A
__global__ void conv_kernel(const float* __restrict__ zx, const float* __restrict__ conv_w,
    const float* __restrict__ conv_b, const float* __restrict__ dt_bias, const float* __restrict__ A_log,
    float* __restrict__ xbc, float* __restrict__ dt2, float* __restrict__ dta, int layer) {
  int r = blockIdx.x, d = blockIdx.y;
  int t = r & (SEQL - 1);
  const float* cw = conv_w + (size_t)((layer * 2 + d) * CDD) * 4;
  const float* cb = conv_b + (layer * 2 + d) * CDD;
  for (int cch = threadIdx.x; cch < CDD; cch += blockDim.x) {
    float acc = cb[cch];
    #pragma unroll
    for (int i = 0; i < 4; i++) {
      int tt = (d == 0) ? (t - 3 + i) : (t + 3 - i);
      if (tt >= 0 && tt < SEQL)
        acc += zx[(size_t)(r - t + tt) * ZXT + d * ZXD + DIi + cch] * cw[cch * 4 + i];
    }
    float sv = acc / (1.f + expf(-acc));   // silu
    xbc[((size_t)(d * RT + r)) * CDD + cch] = sv;
  }
  if (threadIdx.x < NHH) {
    int hh = threadIdx.x;
    float xv = zx[(size_t)r * ZXT + d * ZXD + DIi + CDD + hh] + dt_bias[(layer * 2 + d) * NHH + hh];
    float dtv = (xv > 20.f) ? xv : log1pf(expf(xv));   // softplus
    float Ah = -expf(A_log[(layer * 2 + d) * NHH + hh]);
    dt2[((size_t)(d * RT + r)) * NHH + hh] = dtv;
    dta[((size_t)(d * RT + r)) * NHH + hh] = dtv * Ah;
  }
}

// Phase 1: per (chunk, head, dir, batch): intra-chunk Y, chunk-state S, gamma, P_t
__global__ __launch_bounds__(256) void chunk_p1(const float* __restrict__ xbc,
    const float* __restrict__ dt2, const float* __restrict__ dta,
    float* __restrict__ ybuf, float* __restrict__ Sbuf, float* __restrict__ gbuf,
    float* __restrict__ Pbuf) {
  int c = blockIdx.x, hd = blockIdx.y, b = blockIdx.z;
  int h = hd >> 1, d = hd & 1;
  int tid = threadIdx.x;
  int rb = b * SEQL;
  __shared__ float Bs[QC][DSs + 1], Cs[QC][DSs + 1], Xs[QC][HDD];
  __shared__ float Ms[QC][QC + 1];
  __shared__ float lam[QC], dts[QC], wss[QC];

  for (int i = tid; i < QC * DSs; i += 256) {
    int s = i >> 5, n = i & 31;
    const float* row = xbc + ((size_t)(d * RT + rb + torig(d, c, s))) * CDD;
    Bs[s][n] = row[DIi + n];
    Cs[s][n] = row[DIi + DSs + n];
  }
  for (int i = tid; i < QC * HDD; i += 256) {
    int s = i >> 6, p = i & 63;
    Xs[s][p] = xbc[((size_t)(d * RT + rb + torig(d, c, s))) * CDD + h * HDD + p];
  }
  if (tid < QC) {  // wave 0: inclusive scan of log-decay
    size_t rr = (size_t)(d * RT + rb + torig(d, c, tid));
    float dtv = dt2[rr * NHH + h];
    float la  = dta[rr * NHH + h];
    dts[tid] = dtv;
    #pragma unroll
    for (int o = 1; o < 64; o <<= 1) { float vv = __shfl_up(la, o); if (tid >= o) la += vv; }
    lam[tid] = la;
    float Pv = expf(la);
    Pbuf[rr * NHH + h] = Pv;
    float lq = __shfl(la, 63);
    wss[tid] = expf(lq - la) * dtv;
    if (tid == 63) gbuf[((b * NHH + h) * 2 + d) * NCH + c] = Pv;
  }
  __syncthreads();
  // M[t][s] = exp(lam_t - lam_s) * dt_s * (C_t . B_s), causal
  for (int i = tid; i < QC * QC; i += 256) {
    int t = i >> 6, s = i & 63;
    float m = 0.f;
    if (s <= t) {
      float g = 0.f;
      #pragma unroll
      for (int n = 0; n < DSs; n++) g += Cs[t][n] * Bs[s][n];
      m = expf(lam[t] - lam[s]) * dts[s] * g;
    }
    Ms[t][s] = m;
  }
  __syncthreads();
  // Y_intra = M @ X  (thread owns fixed p, 16 t values)
  {
    int p = tid & 63, t0 = tid >> 6;
    float y[16];
    #pragma unroll
    for (int j = 0; j < 16; j++) y[j] = 0.f;
    for (int s = 0; s < QC; s++) {
      float xv = Xs[s][p];
      #pragma unroll
      for (int j = 0; j < 16; j++) y[j] += Ms[t0 + 4 * j][s] * xv;
    }
    #pragma unroll
    for (int j = 0; j < 16; j++) {
      int t = t0 + 4 * j;
      ybuf[((size_t)(d * RT + rb + torig(d, c, t))) * DIi + h * HDD + p] = y[j];
    }
  }
  // S[p][n] = sum_s wss_s * X[s][p] * B[s][n]
  {
    int n = tid & 31, p0 = tid >> 5;
    float sa[8];
    #pragma unroll
    for (int j = 0; j < 8; j++) sa[j] = 0.f;
    for (int s = 0; s < QC; s++) {
      float wb = wss[s] * Bs[s][n];
      #pragma unroll
      for (int j = 0; j < 8; j++) sa[j] += Xs[s][p0 + 8 * j] * wb;
    }
    size_t base = ((size_t)((b * NHH + h) * 2 + d) * NCH + c) * 2048;
    #pragma unroll
    for (int j = 0; j < 8; j++) Sbuf[base + (size_t)(p0 + 8 * j) * DSs + n] = sa[j];
  }
}

// Phase 2: sequential over 32 chunks; writes H_prev (state entering each chunk)
__global__ void chunk_p2(const float* __restrict__ Sbuf, const float* __restrict__ gbuf,
                         float* __restrict__ Hbuf) {
  int bhd = blockIdx.x;          // (b*8+h)*2+d
  int p = threadIdx.x;           // 64
  float H[DSs];
  #pragma unroll
  for (int n = 0; n < DSs; n++) H[n] = 0.f;
  const float* Sb = Sbuf + (size_t)bhd * NCH * 2048;
  float* Hb = Hbuf + (size_t)bhd * NCH * 2048;
  const float* gb = gbuf + bhd * NCH;
  for (int c = 0; c < NCH; c++) {
    #pragma unroll
    for (int n = 0; n < DSs; n++) Hb[(size_t)c * 2048 + p * DSs + n] = H[n];
    float g = gb[c];
    #pragma unroll
    for (int n = 0; n < DSs; n++) H[n] = g * H[n] + Sb[(size_t)c * 2048 + p * DSs + n];
  }
}

// Phase 3: Y += P_t * (C_t @ H_prev^T) + D * x
__global__ __launch_bounds__(256) void chunk_p3(const float* __restrict__ xbc,
    const float* __restrict__ Pbuf, const float* __restrict__ Hbuf,
    const float* __restrict__ Dvec, float* __restrict__ ybuf, int layer) {
  int c = blockIdx.x, hd = blockIdx.y, b = blockIdx.z;
  int h = hd >> 1, d = hd & 1;
  int tid = threadIdx.x;
  int rb = b * SEQL;
  __shared__ float Cs[QC][DSs + 1], Hs[HDD][DSs + 1];
  __shared__ float Ps[QC];
  for (int i = tid; i < QC * DSs; i += 256) {
    int s = i >> 5, n = i & 31;
    Cs[s][n] = xbc[((size_t)(d * RT + rb + torig(d, c, s))) * CDD + DIi + DSs + n];
  }
  {
    size_t hb = ((size_t)((b * NHH + h) * 2 + d) * NCH + c) * 2048;
    for (int i = tid; i < HDD * DSs; i += 256) Hs[i >> 5][i & 31] = Hbuf[hb + i];
  }
  if (tid < QC) Ps[tid] = Pbuf[((size_t)(d * RT + rb + torig(d, c, tid))) * NHH + h];
  __syncthreads();
  float Dv = Dvec[(layer * 2 + d) * NHH + h];
  for (int i = tid; i < QC * HDD; i += 256) {
    int t = i >> 6, p = i & 63;
    float acc = 0.f;
    #pragma unroll
    for (int n = 0; n < DSs; n++) acc += Cs[t][n] * Hs[p][n];
    size_t rr = (size_t)(d * RT + rb + torig(d, c, t));
    float xv = xbc[rr * CDD + h * HDD + p];
    ybuf[rr * DIi + h * HDD + p] += Ps[t] * acc + Dv * xv;
  }
}

// gate (silu(z)) + RMSNorm + gnorm, write bf16 into concatenated out-proj input
__global__ void gate_kernel(const float* __restrict__ zx, const float* __restrict__ ybuf,
                            const float* __restrict__ gnorm, bf16_t* __restrict__ ycat, int layer) {
  int r = blockIdx.x, d = blockIdx.y, lane = threadIdx.x;  // 64 threads
  const float* yrow = ybuf + ((size_t)(d * RT + r)) * DIi;
  const float* zrow = zx + (size_t)r * ZXT + d * ZXD;
  const float* gw = gnorm + (layer * 2 + d) * DIi;
  float g[8]; float ss = 0.f;
  #pragma unroll
  for (int j = 0; j < 8; j++) {
    int e = j * 64 + lane;
    float y = yrow[e];
    float z = zrow[e];
    float v = y * z / (1.f + expf(-z));
    g[j] = v; ss += v * v;
  }
  #pragma unroll
  for (int o = 32; o; o >>= 1) ss += __shfl_xor(ss, o);
  float sc = rsqrtf(ss * (1.f / DIi) + EPSV);
  #pragma unroll
  for (int j = 0; j < 8; j++) {
    int e = j * 64 + lane;
    ycat[(size_t)r * 1024 + d * DIi + e] = __float2bfloat16(g[j] * sc * gw[e]);
  }
}

extern "C" void kernel_launch(void* const* d_in, const int* in_sizes, int n_in,
                              void* d_out, int out_size, void* d_ws, size_t ws_size,
                              hipStream_t stream) {
  const float* x_in    = (const float*)d_in[0];
  const void*  maskp   = (const void*)d_in[1];
  const float* in_w    = (const float*)d_in[2];
  const float* conv_w  = (const float*)d_in[3];
  const float* conv_b  = (const float*)d_in[4];
  const float* dt_bias = (const float*)d_in[5];
  const float* A_log   = (const float*)d_in[6];
  const float* Dvec    = (const float*)d_in[7];
  const float* gnorm_w = (const float*)d_in[8];
  const float* out_w   = (const float*)d_in[9];
  const float* ln_w    = (const float*)d_in[10];
  const float* ln_b    = (const float*)d_in[11];

  char* ws = (char*)d_ws;
  size_t off = 0;
  auto alloc = [&](size_t bytes) -> void* {
    void* p = ws + off; off += (bytes + 255) & ~(size_t)255; return p;
  };
  float*  x_cur   = (float*)alloc((size_t)RT * DMm * 4);
  bf16_t* h_bf    = (bf16_t*)alloc((size_t)RT * DMm * 2);
  float*  zx      = (float*)alloc((size_t)RT * ZXT * 4);
  float*  xbc     = (float*)alloc((size_t)2 * RT * CDD * 4);
  float*  dt2     = (float*)alloc((size_t)2 * RT * NHH * 4);
  float*  dta     = (float*)alloc((size_t)2 * RT * NHH * 4);
  float*  Pbuf    = (float*)alloc((size_t)2 * RT * NHH * 4);
  float*  ybuf    = (float*)alloc((size_t)2 * RT * DIi * 4);
  bf16_t* ycat    = (bf16_t*)alloc((size_t)RT * 1024 * 2);
  float*  Sbuf    = (float*)alloc((size_t)64 * NCH * 2048 * 4);
  float*  Hbuf    = (float*)alloc((size_t)64 * NCH * 2048 * 4);
  float*  gbuf    = (float*)alloc((size_t)64 * NCH * 4);
  bf16_t* inw_bf  = (bf16_t*)alloc((size_t)NLAY * ZXT * DMm * 2);
  bf16_t* wcat_bf = (bf16_t*)alloc((size_t)NLAY * DMm * 1024 * 2);
  int*    mflag   = (int*)alloc(256);
  // total ~211 MB

  hipMemcpyAsync(x_cur, x_in, (size_t)RT * DMm * 4, hipMemcpyDeviceToDevice, stream);
  detect_mask<<<1, 256, 0, stream>>>((const unsigned char*)maskp, mflag);
  cvt_weights<<<256, 256, 0, stream>>>(in_w, out_w, inw_bf, wcat_bf);

  for (int layer = 0; layer < NLAY; layer++) {
    ln_kernel<<<RT, 64, 0, stream>>>(x_cur, h_bf, ln_w, ln_b);
    gemm_k<0><<<dim3((ZXT + 63) / 64, RT / 64), 256, 0, stream>>>(
        h_bf, inw_bf + (size_t)layer * ZXT * DMm, zx, RT, ZXT, DMm, ZXT, nullptr, mflag);
    conv_kernel<<<dim3(RT, 2), 192, 0, stream>>>(zx, conv_w, conv_b, dt_bias, A_log,
                                                 xbc, dt2, dta, layer);
    chunk_p1<<<dim3(NCH, 16, NB), 256, 0, stream>>>(xbc, dt2, dta, ybuf, Sbuf, gbuf, Pbuf);
    chunk_p2<<<64, 64, 0, stream>>>(Sbuf, gbuf, Hbuf);
    chunk_p3<<<dim3(NCH, 16, NB), 256, 0, stream>>>(xbc, Pbuf, Hbuf, Dvec, ybuf, layer);
    gate_kernel<<<dim3(RT, 2), 64, 0, stream>>>(zx, ybuf, gnorm_w, ycat, layer);
    gemm_k<1><<<dim3(DMm / 64, RT / 64), 256, 0, stream>>>(
        ycat, wcat_bf + (size_t)layer * DMm * 1024, x_cur, RT, DMm, 1024, DMm, maskp, mflag);
  }
  final_ln<<<RT, 64, 0, stream>>>(x_cur, maskp, mflag, ln_w, ln_b, (float*)d_out);
}

// Round 2
// 420.826 us; speedup vs baseline: 1.3667x; 1.3667x over previous
//
#include <hip/hip_runtime.h>
#include <hip/hip_bf16.h>
#include <math.h>

#define SEQL 2048
#define NB 4
#define DMm 256
#define DIi 512
#define DSs 32
#define NHH 8
#define HDD 64
#define CDD 576
#define ZXD 1096
#define ZXT 2192
#define NLAY 2
#define QC 64
#define NCH 32
#define RT 8192
#define EPSV 1e-5f

typedef __hip_bfloat16 bf16_t;
using short8 = __attribute__((ext_vector_type(8))) short;
using f32x4  = __attribute__((ext_vector_type(4))) float;

__device__ __forceinline__ int torig(int d, int c, int s) {
  int v = c * QC + s;
  return d ? (SEQL - 1 - v) : v;
}

__device__ __forceinline__ int is_masked(const void* mask, const int* mflag, int r) {
  return (*mflag) ? (int)(((const unsigned char*)mask)[r] != 0)
                  : (int)(((const int*)mask)[r] != 0);
}

// mask dtype detection: int32 {0,1} has all bytes at pos%4!=0 equal to 0;
// bool8 has ~half nonzero. Reading RT bytes is in-bounds for both layouts.
__global__ void detect_mask(const unsigned char* __restrict__ m, int* __restrict__ flag) {
  __shared__ int any;
  if (threadIdx.x == 0) any = 0;
  __syncthreads();
  int a = 0;
  for (int i = threadIdx.x; i < RT; i += blockDim.x)
    if ((i & 3) && m[i]) a = 1;
  if (a) atomicOr(&any, 1);
  __syncthreads();
  if (threadIdx.x == 0) *flag = any;
}

__global__ void cvt_weights(const float* __restrict__ in_w, const float* __restrict__ out_w,
                            bf16_t* __restrict__ inw_bf, bf16_t* __restrict__ wcat_bf) {
  const int n1 = NLAY * ZXT * DMm;
  const int n2 = NLAY * DMm * 1024;
  for (int idx = blockIdx.x * blockDim.x + threadIdx.x; idx < n1 + n2; idx += gridDim.x * blockDim.x) {
    if (idx < n1) {
      inw_bf[idx] = __float2bfloat16(in_w[idx]);   // [l][dir*1096+e][k] == source flat layout
    } else {
      int j = idx - n1;                            // wcat: [l][d(256)][k(1024)], k = dir*512+e
      int l = j / (DMm * 1024);
      int rem = j % (DMm * 1024);
      int dd = rem >> 10, k = rem & 1023;
      int dir = k >> 9, e = k & 511;
      wcat_bf[j] = __float2bfloat16(out_w[((size_t)((l * 2 + dir) * DMm) + dd) * DIi + e]);
    }
  }
}

__global__ void ln_kernel(const float* __restrict__ x, bf16_t* __restrict__ h,
                          const float* __restrict__ lnw, const float* __restrict__ lnb) {
  int r = blockIdx.x, lane = threadIdx.x;   // 64 threads, 4 cols each
  float4 v = ((const float4*)(x + (size_t)r * DMm))[lane];
  float s = v.x + v.y + v.z + v.w;
  #pragma unroll
  for (int o = 32; o; o >>= 1) s += __shfl_xor(s, o);
  float mu = s * (1.f / DMm);
  float d0 = v.x - mu, d1 = v.y - mu, d2 = v.z - mu, d3 = v.w - mu;
  float q = d0*d0 + d1*d1 + d2*d2 + d3*d3;
  #pragma unroll
  for (int o = 32; o; o >>= 1) q += __shfl_xor(q, o);
  float rstd = rsqrtf(q * (1.f / DMm) + EPSV);
  float4 w  = ((const float4*)lnw)[lane];
  float4 bb = ((const float4*)lnb)[lane];
  union { bf16_t o4[4]; uint2 u; } out;
  out.o4[0] = __float2bfloat16(d0 * rstd * w.x + bb.x);
  out.o4[1] = __float2bfloat16(d1 * rstd * w.y + bb.y);
  out.o4[2] = __float2bfloat16(d2 * rstd * w.z + bb.z);
  out.o4[3] = __float2bfloat16(d3 * rstd * w.w + bb.w);
  ((uint2*)(h + (size_t)r * DMm))[lane] = out.u;
}

__global__ void final_ln(const float* __restrict__ x, const void* __restrict__ mask,
                         const int* __restrict__ mflag,
                         const float* __restrict__ lnw, const float* __restrict__ lnb,
                         float* __restrict__ out) {
  int r = blockIdx.x, lane = threadIdx.x;
  float4 v = ((const float4*)(x + (size_t)r * DMm))[lane];
  float s = v.x + v.y + v.z + v.w;
  #pragma unroll
  for (int o = 32; o; o >>= 1) s += __shfl_xor(s, o);
  float mu = s * (1.f / DMm);
  float d0 = v.x - mu, d1 = v.y - mu, d2 = v.z - mu, d3 = v.w - mu;
  float q = d0*d0 + d1*d1 + d2*d2 + d3*d3;
  #pragma unroll
  for (int o = 32; o; o >>= 1) q += __shfl_xor(q, o);
  float rstd = rsqrtf(q * (1.f / DMm) + EPSV);
  float4 w  = ((const float4*)lnw)[lane];
  float4 bb = ((const float4*)lnb)[lane];
  float4 o4;
  if (is_masked(mask, mflag, r)) { o4.x = o4.y = o4.z = o4.w = 0.f; }
  else {
    o4.x = d0 * rstd * w.x + bb.x; o4.y = d1 * rstd * w.y + bb.y;
    o4.z = d2 * rstd * w.z + bb.z; o4.w = d3 * rstd * w.w + bb.w;
  }
  ((float4*)(out + (size_t)r * DMm))[lane] = o4;
}

// C = A(MxK) * Bw(NxK)^T ; bf16 inputs, fp32 out. EPI=0: store. EPI=1: masked +=.
template<int EPI>
__global__ __launch_bounds__(256) void gemm_k(const bf16_t* __restrict__ A, const bf16_t* __restrict__ Bw,
    float* __restrict__ C, int M, int N, int K, int ldc,
    const void* __restrict__ mask, const int* __restrict__ mflag) {
  __shared__ bf16_t As[64][40];   // pad 32->40 to spread banks
  __shared__ bf16_t Bs[64][40];
  int n0 = blockIdx.x * 64, m0 = blockIdx.y * 64;
  int tid = threadIdx.x, lane = tid & 63, wid = tid >> 6;
  f32x4 acc[4] = {};
  int sr = tid >> 2, sk = (tid & 3) * 8;
  for (int k0 = 0; k0 < K; k0 += 32) {
    short8 av = *(const short8*)(A + (size_t)(m0 + sr) * K + k0 + sk);
    *(short8*)&As[sr][sk] = av;
    int bn = n0 + sr;
    short8 bv = {0,0,0,0,0,0,0,0};
    if (bn < N) bv = *(const short8*)(Bw + (size_t)bn * K + k0 + sk);
    *(short8*)&Bs[sr][sk] = bv;
    __syncthreads();
    short8 af = *(const short8*)&As[wid * 16 + (lane & 15)][(lane >> 4) * 8];
    #pragma unroll
    for (int nt = 0; nt < 4; nt++) {
      short8 bf = *(const short8*)&Bs[nt * 16 + (lane & 15)][(lane >> 4) * 8];
      acc[nt] = __builtin_amdgcn_mfma_f32_16x16x32_bf16(af, bf, acc[nt], 0, 0, 0);
    }
    __syncthreads();
  }
  #pragma unroll
  for (int nt = 0; nt < 4; nt++) {
    int col = n0 + nt * 16 + (lane & 15);
    if (col < N) {
      #pragma unroll
      for (int j = 0; j < 4; j++) {
        int row = m0 + wid * 16 + (lane >> 4) * 4 + j;
        if (EPI == 0) C[(size_t)row * ldc + col] = acc[nt][j];
        else if (!is_masked(mask, mflag, row)) C[(size_t)row * ldc + col] += acc[nt][j];
      }
    }
  }
}

// depthwise causal conv (dir-aware) + silu, and dt/dt*A
__global__ void conv_kernel(const float* __restrict__ zx, const float* __restrict__ conv_w,
    const float* __restrict__ conv_b, const float* __restrict__ dt_bias, const float* __restrict__ A_log,
    float* __restrict__ xbc, float* __restrict__ dt2, float* __restrict__ dta, int layer) {
  int r = blockIdx.x, d = blockIdx.y;
  int t = r & (SEQL - 1);
  const float* cw = conv_w + (size_t)((layer * 2 + d) * CDD) * 4;
  const float* cb = conv_b + (layer * 2 + d) * CDD;
  for (int cch = threadIdx.x; cch < CDD; cch += blockDim.x) {
    float acc = cb[cch];
    #pragma unroll
    for (int i = 0; i < 4; i++) {
      int tt = (d == 0) ? (t - 3 + i) : (t + 3 - i);
      if (tt >= 0 && tt < SEQL)
        acc += zx[(size_t)(r - t + tt) * ZXT + d * ZXD + DIi + cch] * cw[cch * 4 + i];
    }
    float sv = acc / (1.f + expf(-acc));   // silu
    xbc[((size_t)(d * RT + r)) * CDD + cch] = sv;
  }
  if (threadIdx.x < NHH) {
    int hh = threadIdx.x;
    float xv = zx[(size_t)r * ZXT + d * ZXD + DIi + CDD + hh] + dt_bias[(layer * 2 + d) * NHH + hh];
    float dtv = (xv > 20.f) ? xv : log1pf(expf(xv));   // softplus
    float Ah = -expf(A_log[(layer * 2 + d) * NHH + hh]);
    dt2[((size_t)(d * RT + r)) * NHH + hh] = dtv;
    dta[((size_t)(d * RT + r)) * NHH + hh] = dtv * Ah;
  }
}

// Phase 1 (MFMA): per (chunk, head, dir, batch): intra-chunk Y, chunk-state S, gamma, P_t
// All matmuls on mfma_f32_16x16x32_bf16; fragment layout matches validated gemm_k:
//   A from As[M][K] rows (8 consec k), B from Bs[N][K] rows, C/D col=lane&15 row=(lane>>4)*4+j
__global__ __launch_bounds__(256) void chunk_p1(const float* __restrict__ xbc,
    const float* __restrict__ dt2, const float* __restrict__ dta,
    float* __restrict__ ybuf, float* __restrict__ Sbuf, float* __restrict__ gbuf,
    float* __restrict__ Pbuf) {
  int c = blockIdx.x, hd = blockIdx.y, b = blockIdx.z;
  int h = hd >> 1, d = hd & 1;
  int tid = threadIdx.x, lane = tid & 63, wid = tid >> 6;
  int rb = b * SEQL;
  __shared__ __align__(16) bf16_t Bs[QC][40];    // B[s][n]
  __shared__ __align__(16) bf16_t Cs[QC][40];    // C[t][n]
  __shared__ __align__(16) bf16_t Xt[QC][72];    // X^T[p][s]
  __shared__ __align__(16) bf16_t Ms[QC][72];    // M[t][s]
  __shared__ __align__(16) bf16_t Btw[DSs][72];  // (w.B)^T[n][s]
  __shared__ float lam[QC], dts[QC], wss[QC];

  for (int i = tid; i < QC * DSs; i += 256) {
    int s = i >> 5, n = i & 31;
    const float* row = xbc + ((size_t)(d * RT + rb + torig(d, c, s))) * CDD + DIi;
    Bs[s][n] = __float2bfloat16(row[n]);
    Cs[s][n] = __float2bfloat16(row[DSs + n]);
  }
  for (int i = tid; i < QC * HDD; i += 256) {
    int s = i >> 6, p = i & 63;
    Xt[p][s] = __float2bfloat16(xbc[((size_t)(d * RT + rb + torig(d, c, s))) * CDD + h * HDD + p]);
  }
  if (tid < QC) {  // wave 0: inclusive scan of log-decay
    size_t rr = (size_t)(d * RT + rb + torig(d, c, tid));
    float dtv = dt2[rr * NHH + h];
    float la  = dta[rr * NHH + h];
    dts[tid] = dtv;
    #pragma unroll
    for (int o = 1; o < 64; o <<= 1) { float vv = __shfl_up(la, o); if (tid >= o) la += vv; }
    lam[tid] = la;
    float Pv = expf(la);
    Pbuf[rr * NHH + h] = Pv;
    float lq = __shfl(la, 63);
    wss[tid] = expf(lq - la) * dtv;
    if (tid == 63) gbuf[((b * NHH + h) * 2 + d) * NCH + c] = Pv;
  }
  __syncthreads();

  // G = C @ B^T (tiles: tr=wid, sc=0..3); M[t][s] = causal exp(lam_t-lam_s)*dt_s*G
  {
    short8 cf = *(const short8*)&Cs[wid * 16 + (lane & 15)][(lane >> 4) * 8];
    int sbase = lane & 15;
    #pragma unroll
    for (int sc = 0; sc < 4; sc++) {
      int s = sc * 16 + sbase;
      if (sc <= wid) {
        short8 bfr = *(const short8*)&Bs[s][(lane >> 4) * 8];
        f32x4 g = {};
        g = __builtin_amdgcn_mfma_f32_16x16x32_bf16(cf, bfr, g, 0, 0, 0);
        float ls = lam[s], dv = dts[s];
        #pragma unroll
        for (int j = 0; j < 4; j++) {
          int t = wid * 16 + (lane >> 4) * 4 + j;
          float m = (s <= t) ? expf(lam[t] - ls) * dv * g[j] : 0.f;
          Ms[t][s] = __float2bfloat16(m);
        }
      } else {
        #pragma unroll
        for (int j = 0; j < 4; j++) Ms[wid * 16 + (lane >> 4) * 4 + j][s] = __float2bfloat16(0.f);
      }
    }
  }
  // Btw[n][s] = wss[s] * B[s][n]
  for (int i = tid; i < DSs * QC; i += 256) {
    int n = i >> 6, s = i & 63;
    Btw[n][s] = __float2bfloat16(wss[s] * __bfloat162float(Bs[s][n]));
  }
  __syncthreads();

  // Y = M @ X^T^T : A=Ms[t][s], B=Xt[p][s]; wave wid owns t-strip
  {
    short8 ma0 = *(const short8*)&Ms[wid * 16 + (lane & 15)][(lane >> 4) * 8];
    short8 ma1 = *(const short8*)&Ms[wid * 16 + (lane & 15)][32 + (lane >> 4) * 8];
    #pragma unroll
    for (int pt = 0; pt < 4; pt++) {
      short8 xb0 = *(const short8*)&Xt[pt * 16 + (lane & 15)][(lane >> 4) * 8];
      short8 xb1 = *(const short8*)&Xt[pt * 16 + (lane & 15)][32 + (lane >> 4) * 8];
      f32x4 ya = {};
      ya = __builtin_amdgcn_mfma_f32_16x16x32_bf16(ma0, xb0, ya, 0, 0, 0);
      ya = __builtin_amdgcn_mfma_f32_16x16x32_bf16(ma1, xb1, ya, 0, 0, 0);
      int p = pt * 16 + (lane & 15);
      #pragma unroll
      for (int j = 0; j < 4; j++) {
        int t = wid * 16 + (lane >> 4) * 4 + j;
        ybuf[((size_t)(d * RT + rb + torig(d, c, t))) * DIi + h * HDD + p] = ya[j];
      }
    }
  }
  // S[p][n] = sum_s Xt[p][s] * Btw[n][s]; wave wid owns p-strip
  {
    short8 xa0 = *(const short8*)&Xt[wid * 16 + (lane & 15)][(lane >> 4) * 8];
    short8 xa1 = *(const short8*)&Xt[wid * 16 + (lane & 15)][32 + (lane >> 4) * 8];
    size_t base = ((size_t)((b * NHH + h) * 2 + d) * NCH + c) * 2048;
    #pragma unroll
    for (int nt = 0; nt < 2; nt++) {
      short8 bw0 = *(const short8*)&Btw[nt * 16 + (lane & 15)][(lane >> 4) * 8];
      short8 bw1 = *(const short8*)&Btw[nt * 16 + (lane & 15)][32 + (lane >> 4) * 8];
      f32x4 sa = {};
      sa = __builtin_amdgcn_mfma_f32_16x16x32_bf16(xa0, bw0, sa, 0, 0, 0);
      sa = __builtin_amdgcn_mfma_f32_16x16x32_bf16(xa1, bw1, sa, 0, 0, 0);
      int n = nt * 16 + (lane & 15);
      #pragma unroll
      for (int j = 0; j < 4; j++) {
        int p = wid * 16 + (lane >> 4) * 4 + j;
        Sbuf[base + (size_t)p * DSs + n] = sa[j];
      }
    }
  }
}

// Phase 2: sequential over 32 chunks; writes H_prev (state entering each chunk)
__global__ void chunk_p2(const float* __restrict__ Sbuf, const float* __restrict__ gbuf,
                         float* __restrict__ Hbuf) {
  int bhd = blockIdx.x;          // (b*8+h)*2+d
  int p = threadIdx.x;           // 64
  float H[DSs];
  #pragma unroll
  for (int n = 0; n < DSs; n++) H[n] = 0.f;
  const float* Sb = Sbuf + (size_t)bhd * NCH * 2048;
  float* Hb = Hbuf + (size_t)bhd * NCH * 2048;
  const float* gb = gbuf + bhd * NCH;
  for (int c = 0; c < NCH; c++) {
    #pragma unroll
    for (int n = 0; n < DSs; n++) Hb[(size_t)c * 2048 + p * DSs + n] = H[n];
    float g = gb[c];
    #pragma unroll
    for (int n = 0; n < DSs; n++) H[n] = g * H[n] + Sb[(size_t)c * 2048 + p * DSs + n];
  }
}

// Phase 3 (MFMA): Y += P_t * (C_t @ H_prev^T) + D * x
__global__ __launch_bounds__(256) void chunk_p3(const float* __restrict__ xbc,
    const float* __restrict__ Pbuf, const float* __restrict__ Hbuf,
    const float* __restrict__ Dvec, float* __restrict__ ybuf, int layer) {
  int c = blockIdx.x, hd = blockIdx.y, b = blockIdx.z;
  int h = hd >> 1, d = hd & 1;
  int tid = threadIdx.x, lane = tid & 63, wid = tid >> 6;
  int rb = b * SEQL;
  __shared__ __align__(16) bf16_t Cs[QC][40];    // C[t][n]
  __shared__ __align__(16) bf16_t Hs[HDD][40];   // H[p][n]
  __shared__ float Ps[QC];
  for (int i = tid; i < QC * DSs; i += 256) {
    int s = i >> 5, n = i & 31;
    Cs[s][n] = __float2bfloat16(xbc[((size_t)(d * RT + rb + torig(d, c, s))) * CDD + DIi + DSs + n]);
  }
  {
    size_t hb = ((size_t)((b * NHH + h) * 2 + d) * NCH + c) * 2048;
    for (int i = tid; i < HDD * DSs; i += 256) Hs[i >> 5][i & 31] = __float2bfloat16(Hbuf[hb + i]);
  }
  if (tid < QC) Ps[tid] = Pbuf[((size_t)(d * RT + rb + torig(d, c, tid))) * NHH + h];
  __syncthreads();
  float Dv = Dvec[(layer * 2 + d) * NHH + h];
  short8 ca = *(const short8*)&Cs[wid * 16 + (lane & 15)][(lane >> 4) * 8];
  #pragma unroll
  for (int pc = 0; pc < 4; pc++) {
    short8 hb = *(const short8*)&Hs[pc * 16 + (lane & 15)][(lane >> 4) * 8];
    f32x4 a = {};
    a = __builtin_amdgcn_mfma_f32_16x16x32_bf16(ca, hb, a, 0, 0, 0);
    int p = pc * 16 + (lane & 15);
    #pragma unroll
    for (int j = 0; j < 4; j++) {
      int t = wid * 16 + (lane >> 4) * 4 + j;
      size_t rr = (size_t)(d * RT + rb + torig(d, c, t));
      float xv = xbc[rr * CDD + h * HDD + p];
      ybuf[rr * DIi + h * HDD + p] += Ps[t] * a[j] + Dv * xv;
    }
  }
}

// gate (silu(z)) + RMSNorm + gnorm, write bf16 into concatenated out-proj input
__global__ void gate_kernel(const float* __restrict__ zx, const float* __restrict__ ybuf,
                            const float* __restrict__ gnorm, bf16_t* __restrict__ ycat, int layer) {
  int r = blockIdx.x, d = blockIdx.y, lane = threadIdx.x;  // 64 threads
  const float* yrow = ybuf + ((size_t)(d * RT + r)) * DIi;
  const float* zrow = zx + (size_t)r * ZXT + d * ZXD;
  const float* gw = gnorm + (layer * 2 + d) * DIi;
  float g[8]; float ss = 0.f;
  #pragma unroll
  for (int j = 0; j < 8; j++) {
    int e = j * 64 + lane;
    float y = yrow[e];
    float z = zrow[e];
    float v = y * z / (1.f + expf(-z));
    g[j] = v; ss += v * v;
  }
  #pragma unroll
  for (int o = 32; o; o >>= 1) ss += __shfl_xor(ss, o);
  float sc = rsqrtf(ss * (1.f / DIi) + EPSV);
  #pragma unroll
  for (int j = 0; j < 8; j++) {
    int e = j * 64 + lane;
    ycat[(size_t)r * 1024 + d * DIi + e] = __float2bfloat16(g[j] * sc * gw[e]);
  }
}

extern "C" void kernel_launch(void* const* d_in, const int* in_sizes, int n_in,
                              void* d_out, int out_size, void* d_ws, size_t ws_size,
                              hipStream_t stream) {
  const float* x_in    = (const float*)d_in[0];
  const void*  maskp   = (const void*)d_in[1];
  const float* in_w    = (const float*)d_in[2];
  const float* conv_w  = (const float*)d_in[3];
  const float* conv_b  = (const float*)d_in[4];
  const float* dt_bias = (const float*)d_in[5];
  const float* A_log   = (const float*)d_in[6];
  const float* Dvec    = (const float*)d_in[7];
  const float* gnorm_w = (const float*)d_in[8];
  const float* out_w   = (const float*)d_in[9];
  const float* ln_w    = (const float*)d_in[10];
  const float* ln_b    = (const float*)d_in[11];

  char* ws = (char*)d_ws;
  size_t off = 0;
  auto alloc = [&](size_t bytes) -> void* {
    void* p = ws + off; off += (bytes + 255) & ~(size_t)255; return p;
  };
  float*  x_cur   = (float*)alloc((size_t)RT * DMm * 4);
  bf16_t* h_bf    = (bf16_t*)alloc((size_t)RT * DMm * 2);
  float*  zx      = (float*)alloc((size_t)RT * ZXT * 4);
  float*  xbc     = (float*)alloc((size_t)2 * RT * CDD * 4);
  float*  dt2     = (float*)alloc((size_t)2 * RT * NHH * 4);
  float*  dta     = (float*)alloc((size_t)2 * RT * NHH * 4);
  float*  Pbuf    = (float*)alloc((size_t)2 * RT * NHH * 4);
  float*  ybuf    = (float*)alloc((size_t)2 * RT * DIi * 4);
  bf16_t* ycat    = (bf16_t*)alloc((size_t)RT * 1024 * 2);
  float*  Sbuf    = (float*)alloc((size_t)64 * NCH * 2048 * 4);
  float*  Hbuf    = (float*)alloc((size_t)64 * NCH * 2048 * 4);
  float*  gbuf    = (float*)alloc((size_t)64 * NCH * 4);
  bf16_t* inw_bf  = (bf16_t*)alloc((size_t)NLAY * ZXT * DMm * 2);
  bf16_t* wcat_bf = (bf16_t*)alloc((size_t)NLAY * DMm * 1024 * 2);
  int*    mflag   = (int*)alloc(256);
  // total ~211 MB

  hipMemcpyAsync(x_cur, x_in, (size_t)RT * DMm * 4, hipMemcpyDeviceToDevice, stream);
  detect_mask<<<1, 256, 0, stream>>>((const unsigned char*)maskp, mflag);
  cvt_weights<<<256, 256, 0, stream>>>(in_w, out_w, inw_bf, wcat_bf);

  for (int layer = 0; layer < NLAY; layer++) {
    ln_kernel<<<RT, 64, 0, stream>>>(x_cur, h_bf, ln_w, ln_b);
    gemm_k<0><<<dim3((ZXT + 63) / 64, RT / 64), 256, 0, stream>>>(
        h_bf, inw_bf + (size_t)layer * ZXT * DMm, zx, RT, ZXT, DMm, ZXT, nullptr, mflag);
    conv_kernel<<<dim3(RT, 2), 192, 0, stream>>>(zx, conv_w, conv_b, dt_bias, A_log,
                                                 xbc, dt2, dta, layer);
    chunk_p1<<<dim3(NCH, 16, NB), 256, 0, stream>>>(xbc, dt2, dta, ybuf, Sbuf, gbuf, Pbuf);
    chunk_p2<<<64, 64, 0, stream>>>(Sbuf, gbuf, Hbuf);
    chunk_p3<<<dim3(NCH, 16, NB), 256, 0, stream>>>(xbc, Pbuf, Hbuf, Dvec, ybuf, layer);
    gate_kernel<<<dim3(RT, 2), 64, 0, stream>>>(zx, ybuf, gnorm_w, ycat, layer);
    gemm_k<1><<<dim3(DMm / 64, RT / 64), 256, 0, stream>>>(
        ycat, wcat_bf + (size_t)layer * DMm * 1024, x_cur, RT, DMm, 1024, DMm, maskp, mflag);
  }
  final_ln<<<RT, 64, 0, stream>>>(x_cur, maskp, mflag, ln_w, ln_b, (float*)d_out);
}

// Round 3
// 369.268 us; speedup vs baseline: 1.5576x; 1.1396x over previous
//
#include <hip/hip_runtime.h>
#include <hip/hip_bf16.h>
#include <math.h>

#define SEQL 2048
#define NB 4
#define DMm 256
#define DIi 512
#define DSs 32
#define NHH 8
#define HDD 64
#define CDD 576
#define ZXD 1096
#define ZXT 2192
#define NLAY 2
#define QC 64
#define NCH 32
#define RT 8192
#define CTT 16
#define EPSV 1e-5f

typedef __hip_bfloat16 bf16_t;
using short8 = __attribute__((ext_vector_type(8))) short;
using f32x4  = __attribute__((ext_vector_type(4))) float;

__device__ __forceinline__ int torig(int d, int c, int s) {
  int v = c * QC + s;
  return d ? (SEQL - 1 - v) : v;
}

__device__ __forceinline__ int is_masked(const void* mask, const int* mflag, int r) {
  return (*mflag) ? (int)(((const unsigned char*)mask)[r] != 0)
                  : (int)(((const int*)mask)[r] != 0);
}

// mask dtype detection: int32 {0,1} has all bytes at pos%4!=0 equal to 0;
// bool8 has ~half nonzero. Reading RT bytes is in-bounds for both layouts.
__global__ void detect_mask(const unsigned char* __restrict__ m, int* __restrict__ flag) {
  __shared__ int any;
  if (threadIdx.x == 0) any = 0;
  __syncthreads();
  int a = 0;
  for (int i = threadIdx.x; i < RT; i += blockDim.x)
    if ((i & 3) && m[i]) a = 1;
  if (a) atomicOr(&any, 1);
  __syncthreads();
  if (threadIdx.x == 0) *flag = any;
}

__global__ void cvt_weights(const float* __restrict__ in_w, const float* __restrict__ out_w,
                            bf16_t* __restrict__ inw_bf, bf16_t* __restrict__ wcat_bf) {
  const int n1 = NLAY * ZXT * DMm;
  const int n2 = NLAY * DMm * 1024;
  for (int idx = blockIdx.x * blockDim.x + threadIdx.x; idx < n1 + n2; idx += gridDim.x * blockDim.x) {
    if (idx < n1) {
      inw_bf[idx] = __float2bfloat16(in_w[idx]);   // [l][dir*1096+e][k] == source flat layout
    } else {
      int j = idx - n1;                            // wcat: [l][d(256)][k(1024)], k = dir*512+e
      int l = j / (DMm * 1024);
      int rem = j % (DMm * 1024);
      int dd = rem >> 10, k = rem & 1023;
      int dir = k >> 9, e = k & 511;
      wcat_bf[j] = __float2bfloat16(out_w[((size_t)((l * 2 + dir) * DMm) + dd) * DIi + e]);
    }
  }
}

__global__ void ln_kernel(const float* __restrict__ x, bf16_t* __restrict__ h,
                          const float* __restrict__ lnw, const float* __restrict__ lnb) {
  int r = blockIdx.x, lane = threadIdx.x;   // 64 threads, 4 cols each
  float4 v = ((const float4*)(x + (size_t)r * DMm))[lane];
  float s = v.x + v.y + v.z + v.w;
  #pragma unroll
  for (int o = 32; o; o >>= 1) s += __shfl_xor(s, o);
  float mu = s * (1.f / DMm);
  float d0 = v.x - mu, d1 = v.y - mu, d2 = v.z - mu, d3 = v.w - mu;
  float q = d0*d0 + d1*d1 + d2*d2 + d3*d3;
  #pragma unroll
  for (int o = 32; o; o >>= 1) q += __shfl_xor(q, o);
  float rstd = rsqrtf(q * (1.f / DMm) + EPSV);
  float4 w  = ((const float4*)lnw)[lane];
  float4 bb = ((const float4*)lnb)[lane];
  union { bf16_t o4[4]; uint2 u; } out;
  out.o4[0] = __float2bfloat16(d0 * rstd * w.x + bb.x);
  out.o4[1] = __float2bfloat16(d1 * rstd * w.y + bb.y);
  out.o4[2] = __float2bfloat16(d2 * rstd * w.z + bb.z);
  out.o4[3] = __float2bfloat16(d3 * rstd * w.w + bb.w);
  ((uint2*)(h + (size_t)r * DMm))[lane] = out.u;
}

__global__ void final_ln(const float* __restrict__ x, const void* __restrict__ mask,
                         const int* __restrict__ mflag,
                         const float* __restrict__ lnw, const float* __restrict__ lnb,
                         float* __restrict__ out) {
  int r = blockIdx.x, lane = threadIdx.x;
  float4 v = ((const float4*)(x + (size_t)r * DMm))[lane];
  float s = v.x + v.y + v.z + v.w;
  #pragma unroll
  for (int o = 32; o; o >>= 1) s += __shfl_xor(s, o);
  float mu = s * (1.f / DMm);
  float d0 = v.x - mu, d1 = v.y - mu, d2 = v.z - mu, d3 = v.w - mu;
  float q = d0*d0 + d1*d1 + d2*d2 + d3*d3;
  #pragma unroll
  for (int o = 32; o; o >>= 1) q += __shfl_xor(q, o);
  float rstd = rsqrtf(q * (1.f / DMm) + EPSV);
  float4 w  = ((const float4*)lnw)[lane];
  float4 bb = ((const float4*)lnb)[lane];
  float4 o4;
  if (is_masked(mask, mflag, r)) { o4.x = o4.y = o4.z = o4.w = 0.f; }
  else {
    o4.x = d0 * rstd * w.x + bb.x; o4.y = d1 * rstd * w.y + bb.y;
    o4.z = d2 * rstd * w.z + bb.z; o4.w = d3 * rstd * w.w + bb.w;
  }
  ((float4*)(out + (size_t)r * DMm))[lane] = o4;
}

// C = A(MxK) * Bw(NxK)^T ; bf16 inputs, fp32 out. EPI=0: store. EPI=1: masked +=.
template<int EPI>
__global__ __launch_bounds__(256) void gemm_k(const bf16_t* __restrict__ A, const bf16_t* __restrict__ Bw,
    float* __restrict__ C, int M, int N, int K, int ldc,
    const void* __restrict__ mask, const int* __restrict__ mflag) {
  __shared__ bf16_t As[64][40];   // pad 32->40 to spread banks
  __shared__ bf16_t Bs[64][40];
  int n0 = blockIdx.x * 64, m0 = blockIdx.y * 64;
  int tid = threadIdx.x, lane = tid & 63, wid = tid >> 6;
  f32x4 acc[4] = {};
  int sr = tid >> 2, sk = (tid & 3) * 8;
  for (int k0 = 0; k0 < K; k0 += 32) {
    short8 av = *(const short8*)(A + (size_t)(m0 + sr) * K + k0 + sk);
    *(short8*)&As[sr][sk] = av;
    int bn = n0 + sr;
    short8 bv = {0,0,0,0,0,0,0,0};
    if (bn < N) bv = *(const short8*)(Bw + (size_t)bn * K + k0 + sk);
    *(short8*)&Bs[sr][sk] = bv;
    __syncthreads();
    short8 af = *(const short8*)&As[wid * 16 + (lane & 15)][(lane >> 4) * 8];
    #pragma unroll
    for (int nt = 0; nt < 4; nt++) {
      short8 bf = *(const short8*)&Bs[nt * 16 + (lane & 15)][(lane >> 4) * 8];
      acc[nt] = __builtin_amdgcn_mfma_f32_16x16x32_bf16(af, bf, acc[nt], 0, 0, 0);
    }
    __syncthreads();
  }
  #pragma unroll
  for (int nt = 0; nt < 4; nt++) {
    int col = n0 + nt * 16 + (lane & 15);
    if (col < N) {
      #pragma unroll
      for (int j = 0; j < 4; j++) {
        int row = m0 + wid * 16 + (lane >> 4) * 4 + j;
        if (EPI == 0) C[(size_t)row * ldc + col] = acc[nt][j];
        else if (!is_masked(mask, mflag, row)) C[(size_t)row * ldc + col] += acc[nt][j];
      }
    }
  }
}

// Time-tiled depthwise conv + silu. Block = (16-step virtual-time tile, b, d),
// 192 threads x 3 channels each (scalar coalesced, 100% lanes). 4-tap reuse
// via rolling register window; each input row fetched ~1.19x instead of ~2x.
__global__ __launch_bounds__(192) void conv_tile(const float* __restrict__ zx,
    const float* __restrict__ conv_w, const float* __restrict__ conv_b,
    float* __restrict__ xbc, int layer) {
  int tile = blockIdx.x, b = blockIdx.y, d = blockIdx.z;
  int v0 = tile * CTT;
  int tid = threadIdx.x;
  const float* cwp = conv_w + (size_t)((layer * 2 + d) * CDD) * 4;
  const float* cbp = conv_b + (layer * 2 + d) * CDD;
  float w[3][4]; float bias[3]; int ch[3];
  #pragma unroll
  for (int j = 0; j < 3; j++) {
    ch[j] = tid + 192 * j;
    bias[j] = cbp[ch[j]];
    #pragma unroll
    for (int i = 0; i < 4; i++) w[j][i] = cwp[ch[j] * 4 + i];
  }
  const float* zbase = zx + (size_t)b * SEQL * ZXT + d * ZXD + DIi;
  float win[3][3];   // win[j][k] = in_v[v-3+k] for channel j (virtual time order)
  #pragma unroll
  for (int k = 0; k < 3; k++) {
    int v = v0 - 3 + k;
    int t = d ? (SEQL - 1 - v) : v;
    bool ok = (v >= 0);
    #pragma unroll
    for (int j = 0; j < 3; j++)
      win[j][k] = ok ? zbase[(size_t)t * ZXT + ch[j]] : 0.f;
  }
  for (int it = 0; it < CTT; it++) {
    int v = v0 + it;
    int t = d ? (SEQL - 1 - v) : v;
    const float* irow = zbase + (size_t)t * ZXT;
    float* orow = xbc + ((size_t)(d * RT + b * SEQL + t)) * CDD;
    #pragma unroll
    for (int j = 0; j < 3; j++) {
      float cur = irow[ch[j]];
      float a = bias[j] + w[j][0] * win[j][0] + w[j][1] * win[j][1]
                        + w[j][2] * win[j][2] + w[j][3] * cur;
      a = a / (1.f + expf(-a));
      orow[ch[j]] = a;
      win[j][0] = win[j][1]; win[j][1] = win[j][2]; win[j][2] = cur;
    }
  }
}

// Phase 1 (MFMA): per (chunk, head, dir, batch): intra-chunk Y, chunk-state S, gamma, P_t
// dt/softplus/lambda computed here directly from zx (dt2/dta buffers eliminated).
__global__ __launch_bounds__(256) void chunk_p1(const float* __restrict__ xbc,
    const float* __restrict__ zx, const float* __restrict__ dt_bias,
    const float* __restrict__ A_log,
    float* __restrict__ ybuf, float* __restrict__ Sbuf, float* __restrict__ gbuf,
    float* __restrict__ Pbuf, int layer) {
  int c = blockIdx.x, hd = blockIdx.y, b = blockIdx.z;
  int h = hd >> 1, d = hd & 1;
  int tid = threadIdx.x, lane = tid & 63, wid = tid >> 6;
  int rb = b * SEQL;
  __shared__ __align__(16) bf16_t Bs[QC][40];    // B[s][n]
  __shared__ __align__(16) bf16_t Cs[QC][40];    // C[t][n]
  __shared__ __align__(16) bf16_t Xt[QC][72];    // X^T[p][s]
  __shared__ __align__(16) bf16_t Ms[QC][72];    // M[t][s]
  __shared__ __align__(16) bf16_t Btw[DSs][72];  // (w.B)^T[n][s]
  __shared__ float lam[QC], dts[QC], wss[QC];

  for (int i = tid; i < QC * DSs; i += 256) {
    int s = i >> 5, n = i & 31;
    const float* row = xbc + ((size_t)(d * RT + rb + torig(d, c, s))) * CDD + DIi;
    Bs[s][n] = __float2bfloat16(row[n]);
    Cs[s][n] = __float2bfloat16(row[DSs + n]);
  }
  for (int i = tid; i < QC * HDD; i += 256) {
    int s = i >> 6, p = i & 63;
    Xt[p][s] = __float2bfloat16(xbc[((size_t)(d * RT + rb + torig(d, c, s))) * CDD + h * HDD + p]);
  }
  if (tid < QC) {  // wave 0: dt from zx, then inclusive scan of log-decay
    int ro = rb + torig(d, c, tid);
    size_t rr = (size_t)d * RT + ro;
    float xv = zx[(size_t)ro * ZXT + d * ZXD + DIi + CDD + h]
             + dt_bias[(layer * 2 + d) * NHH + h];
    float dtv = (xv > 20.f) ? xv : log1pf(expf(xv));
    float Ah = -expf(A_log[(layer * 2 + d) * NHH + h]);
    float la = dtv * Ah;
    dts[tid] = dtv;
    #pragma unroll
    for (int o = 1; o < 64; o <<= 1) { float vv = __shfl_up(la, o); if (tid >= o) la += vv; }
    lam[tid] = la;
    float Pv = expf(la);
    Pbuf[rr * NHH + h] = Pv;
    float lq = __shfl(la, 63);
    wss[tid] = expf(lq - la) * dtv;
    if (tid == 63) gbuf[((b * NHH + h) * 2 + d) * NCH + c] = Pv;
  }
  __syncthreads();

  // G = C @ B^T (tiles: tr=wid, sc=0..3); M[t][s] = causal exp(lam_t-lam_s)*dt_s*G
  {
    short8 cf = *(const short8*)&Cs[wid * 16 + (lane & 15)][(lane >> 4) * 8];
    int sbase = lane & 15;
    #pragma unroll
    for (int sc = 0; sc < 4; sc++) {
      int s = sc * 16 + sbase;
      if (sc <= wid) {
        short8 bfr = *(const short8*)&Bs[s][(lane >> 4) * 8];
        f32x4 g = {};
        g = __builtin_amdgcn_mfma_f32_16x16x32_bf16(cf, bfr, g, 0, 0, 0);
        float ls = lam[s], dv = dts[s];
        #pragma unroll
        for (int j = 0; j < 4; j++) {
          int t = wid * 16 + (lane >> 4) * 4 + j;
          float m = (s <= t) ? expf(lam[t] - ls) * dv * g[j] : 0.f;
          Ms[t][s] = __float2bfloat16(m);
        }
      } else {
        #pragma unroll
        for (int j = 0; j < 4; j++) Ms[wid * 16 + (lane >> 4) * 4 + j][s] = __float2bfloat16(0.f);
      }
    }
  }
  // Btw[n][s] = wss[s] * B[s][n]
  for (int i = tid; i < DSs * QC; i += 256) {
    int n = i >> 6, s = i & 63;
    Btw[n][s] = __float2bfloat16(wss[s] * __bfloat162float(Bs[s][n]));
  }
  __syncthreads();

  // Y = M @ X^T^T : A=Ms[t][s], B=Xt[p][s]; wave wid owns t-strip
  {
    short8 ma0 = *(const short8*)&Ms[wid * 16 + (lane & 15)][(lane >> 4) * 8];
    short8 ma1 = *(const short8*)&Ms[wid * 16 + (lane & 15)][32 + (lane >> 4) * 8];
    #pragma unroll
    for (int pt = 0; pt < 4; pt++) {
      short8 xb0 = *(const short8*)&Xt[pt * 16 + (lane & 15)][(lane >> 4) * 8];
      short8 xb1 = *(const short8*)&Xt[pt * 16 + (lane & 15)][32 + (lane >> 4) * 8];
      f32x4 ya = {};
      ya = __builtin_amdgcn_mfma_f32_16x16x32_bf16(ma0, xb0, ya, 0, 0, 0);
      ya = __builtin_amdgcn_mfma_f32_16x16x32_bf16(ma1, xb1, ya, 0, 0, 0);
      int p = pt * 16 + (lane & 15);
      #pragma unroll
      for (int j = 0; j < 4; j++) {
        int t = wid * 16 + (lane >> 4) * 4 + j;
        ybuf[((size_t)(d * RT + rb + torig(d, c, t))) * DIi + h * HDD + p] = ya[j];
      }
    }
  }
  // S[p][n] = sum_s Xt[p][s] * Btw[n][s]; wave wid owns p-strip
  {
    short8 xa0 = *(const short8*)&Xt[wid * 16 + (lane & 15)][(lane >> 4) * 8];
    short8 xa1 = *(const short8*)&Xt[wid * 16 + (lane & 15)][32 + (lane >> 4) * 8];
    size_t base = ((size_t)((b * NHH + h) * 2 + d) * NCH + c) * 2048;
    #pragma unroll
    for (int nt = 0; nt < 2; nt++) {
      short8 bw0 = *(const short8*)&Btw[nt * 16 + (lane & 15)][(lane >> 4) * 8];
      short8 bw1 = *(const short8*)&Btw[nt * 16 + (lane & 15)][32 + (lane >> 4) * 8];
      f32x4 sa = {};
      sa = __builtin_amdgcn_mfma_f32_16x16x32_bf16(xa0, bw0, sa, 0, 0, 0);
      sa = __builtin_amdgcn_mfma_f32_16x16x32_bf16(xa1, bw1, sa, 0, 0, 0);
      int n = nt * 16 + (lane & 15);
      #pragma unroll
      for (int j = 0; j < 4; j++) {
        int p = wid * 16 + (lane >> 4) * 4 + j;
        Sbuf[base + (size_t)p * DSs + n] = sa[j];
      }
    }
  }
}

// Phase 2: sequential over 32 chunks; writes H_prev (state entering each chunk)
__global__ void chunk_p2(const float* __restrict__ Sbuf, const float* __restrict__ gbuf,
                         float* __restrict__ Hbuf) {
  int bhd = blockIdx.x;          // (b*8+h)*2+d
  int p = threadIdx.x;           // 64
  float H[DSs];
  #pragma unroll
  for (int n = 0; n < DSs; n++) H[n] = 0.f;
  const float* Sb = Sbuf + (size_t)bhd * NCH * 2048;
  float* Hb = Hbuf + (size_t)bhd * NCH * 2048;
  const float* gb = gbuf + bhd * NCH;
  for (int c = 0; c < NCH; c++) {
    #pragma unroll
    for (int n = 0; n < DSs; n++) Hb[(size_t)c * 2048 + p * DSs + n] = H[n];
    float g = gb[c];
    #pragma unroll
    for (int n = 0; n < DSs; n++) H[n] = g * H[n] + Sb[(size_t)c * 2048 + p * DSs + n];
  }
}

// Phase 3 (MFMA): Y += P_t * (C_t @ H_prev^T) + D * x
__global__ __launch_bounds__(256) void chunk_p3(const float* __restrict__ xbc,
    const float* __restrict__ Pbuf, const float* __restrict__ Hbuf,
    const float* __restrict__ Dvec, float* __restrict__ ybuf, int layer) {
  int c = blockIdx.x, hd = blockIdx.y, b = blockIdx.z;
  int h = hd >> 1, d = hd & 1;
  int tid = threadIdx.x, lane = tid & 63, wid = tid >> 6;
  int rb = b * SEQL;
  __shared__ __align__(16) bf16_t Cs[QC][40];    // C[t][n]
  __shared__ __align__(16) bf16_t Hs[HDD][40];   // H[p][n]
  __shared__ float Ps[QC];
  for (int i = tid; i < QC * DSs; i += 256) {
    int s = i >> 5, n = i & 31;
    Cs[s][n] = __float2bfloat16(xbc[((size_t)(d * RT + rb + torig(d, c, s))) * CDD + DIi + DSs + n]);
  }
  {
    size_t hb = ((size_t)((b * NHH + h) * 2 + d) * NCH + c) * 2048;
    for (int i = tid; i < HDD * DSs; i += 256) Hs[i >> 5][i & 31] = __float2bfloat16(Hbuf[hb + i]);
  }
  if (tid < QC) Ps[tid] = Pbuf[((size_t)(d * RT + rb + torig(d, c, tid))) * NHH + h];
  __syncthreads();
  float Dv = Dvec[(layer * 2 + d) * NHH + h];
  short8 ca = *(const short8*)&Cs[wid * 16 + (lane & 15)][(lane >> 4) * 8];
  #pragma unroll
  for (int pc = 0; pc < 4; pc++) {
    short8 hb = *(const short8*)&Hs[pc * 16 + (lane & 15)][(lane >> 4) * 8];
    f32x4 a = {};
    a = __builtin_amdgcn_mfma_f32_16x16x32_bf16(ca, hb, a, 0, 0, 0);
    int p = pc * 16 + (lane & 15);
    #pragma unroll
    for (int j = 0; j < 4; j++) {
      int t = wid * 16 + (lane >> 4) * 4 + j;
      size_t rr = (size_t)(d * RT + rb + torig(d, c, t));
      float xv = xbc[rr * CDD + h * HDD + p];
      ybuf[rr * DIi + h * HDD + p] += Ps[t] * a[j] + Dv * xv;
    }
  }
}

// gate (silu(z)) + RMSNorm + gnorm, write bf16 into concatenated out-proj input
__global__ void gate_kernel(const float* __restrict__ zx, const float* __restrict__ ybuf,
                            const float* __restrict__ gnorm, bf16_t* __restrict__ ycat, int layer) {
  int r = blockIdx.x, d = blockIdx.y, lane = threadIdx.x;  // 64 threads
  const float* yrow = ybuf + ((size_t)(d * RT + r)) * DIi;
  const float* zrow = zx + (size_t)r * ZXT + d * ZXD;
  const float* gw = gnorm + (layer * 2 + d) * DIi;
  float g[8]; float ss = 0.f;
  #pragma unroll
  for (int j = 0; j < 8; j++) {
    int e = j * 64 + lane;
    float y = yrow[e];
    float z = zrow[e];
    float v = y * z / (1.f + expf(-z));
    g[j] = v; ss += v * v;
  }
  #pragma unroll
  for (int o = 32; o; o >>= 1) ss += __shfl_xor(ss, o);
  float sc = rsqrtf(ss * (1.f / DIi) + EPSV);
  #pragma unroll
  for (int j = 0; j < 8; j++) {
    int e = j * 64 + lane;
    ycat[(size_t)r * 1024 + d * DIi + e] = __float2bfloat16(g[j] * sc * gw[e]);
  }
}

extern "C" void kernel_launch(void* const* d_in, const int* in_sizes, int n_in,
                              void* d_out, int out_size, void* d_ws, size_t ws_size,
                              hipStream_t stream) {
  const float* x_in    = (const float*)d_in[0];
  const void*  maskp   = (const void*)d_in[1];
  const float* in_w    = (const float*)d_in[2];
  const float* conv_w  = (const float*)d_in[3];
  const float* conv_b  = (const float*)d_in[4];
  const float* dt_bias = (const float*)d_in[5];
  const float* A_log   = (const float*)d_in[6];
  const float* Dvec    = (const float*)d_in[7];
  const float* gnorm_w = (const float*)d_in[8];
  const float* out_w   = (const float*)d_in[9];
  const float* ln_w    = (const float*)d_in[10];
  const float* ln_b    = (const float*)d_in[11];

  char* ws = (char*)d_ws;
  size_t off = 0;
  auto alloc = [&](size_t bytes) -> void* {
    void* p = ws + off; off += (bytes + 255) & ~(size_t)255; return p;
  };
  float*  x_cur   = (float*)alloc((size_t)RT * DMm * 4);
  bf16_t* h_bf    = (bf16_t*)alloc((size_t)RT * DMm * 2);
  float*  zx      = (float*)alloc((size_t)RT * ZXT * 4);
  float*  xbc     = (float*)alloc((size_t)2 * RT * CDD * 4);
  float*  Pbuf    = (float*)alloc((size_t)2 * RT * NHH * 4);
  float*  ybuf    = (float*)alloc((size_t)2 * RT * DIi * 4);
  bf16_t* ycat    = (bf16_t*)alloc((size_t)RT * 1024 * 2);
  float*  Sbuf    = (float*)alloc((size_t)64 * NCH * 2048 * 4);
  float*  Hbuf    = (float*)alloc((size_t)64 * NCH * 2048 * 4);
  float*  gbuf    = (float*)alloc((size_t)64 * NCH * 4);
  bf16_t* inw_bf  = (bf16_t*)alloc((size_t)NLAY * ZXT * DMm * 2);
  bf16_t* wcat_bf = (bf16_t*)alloc((size_t)NLAY * DMm * 1024 * 2);
  int*    mflag   = (int*)alloc(256);

  hipMemcpyAsync(x_cur, x_in, (size_t)RT * DMm * 4, hipMemcpyDeviceToDevice, stream);
  detect_mask<<<1, 256, 0, stream>>>((const unsigned char*)maskp, mflag);
  cvt_weights<<<256, 256, 0, stream>>>(in_w, out_w, inw_bf, wcat_bf);

  for (int layer = 0; layer < NLAY; layer++) {
    ln_kernel<<<RT, 64, 0, stream>>>(x_cur, h_bf, ln_w, ln_b);
    gemm_k<0><<<dim3((ZXT + 63) / 64, RT / 64), 256, 0, stream>>>(
        h_bf, inw_bf + (size_t)layer * ZXT * DMm, zx, RT, ZXT, DMm, ZXT, nullptr, mflag);
    conv_tile<<<dim3(SEQL / CTT, NB, 2), 192, 0, stream>>>(zx, conv_w, conv_b, xbc, layer);
    chunk_p1<<<dim3(NCH, 16, NB), 256, 0, stream>>>(xbc, zx, dt_bias, A_log,
                                                    ybuf, Sbuf, gbuf, Pbuf, layer);
    chunk_p2<<<64, 64, 0, stream>>>(Sbuf, gbuf, Hbuf);
    chunk_p3<<<dim3(NCH, 16, NB), 256, 0, stream>>>(xbc, Pbuf, Hbuf, Dvec, ybuf, layer);
    gate_kernel<<<dim3(RT, 2), 64, 0, stream>>>(zx, ybuf, gnorm_w, ycat, layer);
    gemm_k<1><<<dim3(DMm / 64, RT / 64), 256, 0, stream>>>(
        ycat, wcat_bf + (size_t)layer * DMm * 1024, x_cur, RT, DMm, 1024, DMm, maskp, mflag);
  }
  final_ln<<<RT, 64, 0, stream>>>(x_cur, maskp, mflag, ln_w, ln_b, (float*)d_out);
}

// Round 4
// 344.833 us; speedup vs baseline: 1.6679x; 1.0709x over previous
//
#include <hip/hip_runtime.h>
#include <hip/hip_bf16.h>
#include <math.h>

#define SEQL 2048
#define NB 4
#define DMm 256
#define DIi 512
#define DSs 32
#define NHH 8
#define HDD 64
#define CDD 576
#define ZXD 1096
#define ZXT 2192
#define NLAY 2
#define QC 64
#define NCH 32
#define RT 8192
#define CTT 16
#define EPSV 1e-5f

typedef __hip_bfloat16 bf16_t;
using short8 = __attribute__((ext_vector_type(8))) short;
using f32x4  = __attribute__((ext_vector_type(4))) float;

__device__ __forceinline__ int torig(int d, int c, int s) {
  int v = c * QC + s;
  return d ? (SEQL - 1 - v) : v;
}

__device__ __forceinline__ int is_masked(const void* mask, const int* mflag, int r) {
  return (*mflag) ? (int)(((const unsigned char*)mask)[r] != 0)
                  : (int)(((const int*)mask)[r] != 0);
}

// mask dtype detection: int32 {0,1} has all bytes at pos%4!=0 equal to 0;
// bool8 has ~half nonzero. Reading RT bytes is in-bounds for both layouts.
__global__ void detect_mask(const unsigned char* __restrict__ m, int* __restrict__ flag) {
  __shared__ int any;
  if (threadIdx.x == 0) any = 0;
  __syncthreads();
  int a = 0;
  for (int i = threadIdx.x; i < RT; i += blockDim.x)
    if ((i & 3) && m[i]) a = 1;
  if (a) atomicOr(&any, 1);
  __syncthreads();
  if (threadIdx.x == 0) *flag = any;
}

__global__ void cvt_weights(const float* __restrict__ in_w, const float* __restrict__ out_w,
                            bf16_t* __restrict__ inw_bf, bf16_t* __restrict__ wcat_bf) {
  const int n1 = NLAY * ZXT * DMm;
  const int n2 = NLAY * DMm * 1024;
  for (int idx = blockIdx.x * blockDim.x + threadIdx.x; idx < n1 + n2; idx += gridDim.x * blockDim.x) {
    if (idx < n1) {
      inw_bf[idx] = __float2bfloat16(in_w[idx]);   // [l][dir*1096+e][k] == source flat layout
    } else {
      int j = idx - n1;                            // wcat: [l][d(256)][k(1024)], k = dir*512+e
      int l = j / (DMm * 1024);
      int rem = j % (DMm * 1024);
      int dd = rem >> 10, k = rem & 1023;
      int dir = k >> 9, e = k & 511;
      wcat_bf[j] = __float2bfloat16(out_w[((size_t)((l * 2 + dir) * DMm) + dd) * DIi + e]);
    }
  }
}

__global__ void ln_kernel(const float* __restrict__ x, bf16_t* __restrict__ h,
                          const float* __restrict__ lnw, const float* __restrict__ lnb) {
  int r = blockIdx.x, lane = threadIdx.x;   // 64 threads, 4 cols each
  float4 v = ((const float4*)(x + (size_t)r * DMm))[lane];
  float s = v.x + v.y + v.z + v.w;
  #pragma unroll
  for (int o = 32; o; o >>= 1) s += __shfl_xor(s, o);
  float mu = s * (1.f / DMm);
  float d0 = v.x - mu, d1 = v.y - mu, d2 = v.z - mu, d3 = v.w - mu;
  float q = d0*d0 + d1*d1 + d2*d2 + d3*d3;
  #pragma unroll
  for (int o = 32; o; o >>= 1) q += __shfl_xor(q, o);
  float rstd = rsqrtf(q * (1.f / DMm) + EPSV);
  float4 w  = ((const float4*)lnw)[lane];
  float4 bb = ((const float4*)lnb)[lane];
  union { bf16_t o4[4]; uint2 u; } out;
  out.o4[0] = __float2bfloat16(d0 * rstd * w.x + bb.x);
  out.o4[1] = __float2bfloat16(d1 * rstd * w.y + bb.y);
  out.o4[2] = __float2bfloat16(d2 * rstd * w.z + bb.z);
  out.o4[3] = __float2bfloat16(d3 * rstd * w.w + bb.w);
  ((uint2*)(h + (size_t)r * DMm))[lane] = out.u;
}

__global__ void final_ln(const float* __restrict__ x, const void* __restrict__ mask,
                         const int* __restrict__ mflag,
                         const float* __restrict__ lnw, const float* __restrict__ lnb,
                         float* __restrict__ out) {
  int r = blockIdx.x, lane = threadIdx.x;
  float4 v = ((const float4*)(x + (size_t)r * DMm))[lane];
  float s = v.x + v.y + v.z + v.w;
  #pragma unroll
  for (int o = 32; o; o >>= 1) s += __shfl_xor(s, o);
  float mu = s * (1.f / DMm);
  float d0 = v.x - mu, d1 = v.y - mu, d2 = v.z - mu, d3 = v.w - mu;
  float q = d0*d0 + d1*d1 + d2*d2 + d3*d3;
  #pragma unroll
  for (int o = 32; o; o >>= 1) q += __shfl_xor(q, o);
  float rstd = rsqrtf(q * (1.f / DMm) + EPSV);
  float4 w  = ((const float4*)lnw)[lane];
  float4 bb = ((const float4*)lnb)[lane];
  float4 o4;
  if (is_masked(mask, mflag, r)) { o4.x = o4.y = o4.z = o4.w = 0.f; }
  else {
    o4.x = d0 * rstd * w.x + bb.x; o4.y = d1 * rstd * w.y + bb.y;
    o4.z = d2 * rstd * w.z + bb.z; o4.w = d3 * rstd * w.w + bb.w;
  }
  ((float4*)(out + (size_t)r * DMm))[lane] = o4;
}

// C = A(MxK) * Bw(NxK)^T ; bf16 inputs.
// EPI=0: store bf16 into Cb (+ f32 dt side-channel cols 1088-1095 / 2184-2191).
// EPI=1: masked += into f32 C.
template<int EPI>
__global__ __launch_bounds__(256) void gemm_k(const bf16_t* __restrict__ A, const bf16_t* __restrict__ Bw,
    float* __restrict__ C, bf16_t* __restrict__ Cb, float* __restrict__ dtf,
    int M, int N, int K, int ldc,
    const void* __restrict__ mask, const int* __restrict__ mflag) {
  __shared__ bf16_t As[64][40];   // pad to spread banks
  __shared__ bf16_t Bs[64][40];
  int n0 = blockIdx.x * 64, m0 = blockIdx.y * 64;
  int tid = threadIdx.x, lane = tid & 63, wid = tid >> 6;
  f32x4 acc[4] = {};
  int sr = tid >> 2, sk = (tid & 3) * 8;
  for (int k0 = 0; k0 < K; k0 += 32) {
    short8 av = *(const short8*)(A + (size_t)(m0 + sr) * K + k0 + sk);
    *(short8*)&As[sr][sk] = av;
    int bn = n0 + sr;
    short8 bv = {0,0,0,0,0,0,0,0};
    if (bn < N) bv = *(const short8*)(Bw + (size_t)bn * K + k0 + sk);
    *(short8*)&Bs[sr][sk] = bv;
    __syncthreads();
    short8 af = *(const short8*)&As[wid * 16 + (lane & 15)][(lane >> 4) * 8];
    #pragma unroll
    for (int nt = 0; nt < 4; nt++) {
      short8 bf = *(const short8*)&Bs[nt * 16 + (lane & 15)][(lane >> 4) * 8];
      acc[nt] = __builtin_amdgcn_mfma_f32_16x16x32_bf16(af, bf, acc[nt], 0, 0, 0);
    }
    __syncthreads();
  }
  #pragma unroll
  for (int nt = 0; nt < 4; nt++) {
    int col = n0 + nt * 16 + (lane & 15);
    if (col < N) {
      #pragma unroll
      for (int j = 0; j < 4; j++) {
        int row = m0 + wid * 16 + (lane >> 4) * 4 + j;
        if (EPI == 0) {
          Cb[(size_t)row * ldc + col] = __float2bfloat16(acc[nt][j]);
          if (col >= 1088 && col < 1096)
            dtf[((size_t)row) * NHH + (col - 1088)] = acc[nt][j];
          else if (col >= 2184)
            dtf[((size_t)RT + row) * NHH + (col - 2184)] = acc[nt][j];
        } else if (!is_masked(mask, mflag, row)) {
          C[(size_t)row * ldc + col] += acc[nt][j];
        }
      }
    }
  }
}

// Time-tiled depthwise conv + silu on bf16 zx. Block = (16-step tile, b, d),
// 192 threads x 3 channels; rolling register window for the 4 taps.
__global__ __launch_bounds__(192) void conv_tile(const bf16_t* __restrict__ zx,
    const float* __restrict__ conv_w, const float* __restrict__ conv_b,
    bf16_t* __restrict__ xbc, int layer) {
  int tile = blockIdx.x, b = blockIdx.y, d = blockIdx.z;
  int v0 = tile * CTT;
  int tid = threadIdx.x;
  const float* cwp = conv_w + (size_t)((layer * 2 + d) * CDD) * 4;
  const float* cbp = conv_b + (layer * 2 + d) * CDD;
  float w[3][4]; float bias[3]; int ch[3];
  #pragma unroll
  for (int j = 0; j < 3; j++) {
    ch[j] = tid + 192 * j;
    bias[j] = cbp[ch[j]];
    #pragma unroll
    for (int i = 0; i < 4; i++) w[j][i] = cwp[ch[j] * 4 + i];
  }
  const bf16_t* zbase = zx + (size_t)b * SEQL * ZXT + d * ZXD + DIi;
  float win[3][3];
  #pragma unroll
  for (int k = 0; k < 3; k++) {
    int v = v0 - 3 + k;
    int t = d ? (SEQL - 1 - v) : v;
    bool ok = (v >= 0);
    #pragma unroll
    for (int j = 0; j < 3; j++)
      win[j][k] = ok ? __bfloat162float(zbase[(size_t)t * ZXT + ch[j]]) : 0.f;
  }
  for (int it = 0; it < CTT; it++) {
    int v = v0 + it;
    int t = d ? (SEQL - 1 - v) : v;
    const bf16_t* irow = zbase + (size_t)t * ZXT;
    bf16_t* orow = xbc + ((size_t)(d * RT + b * SEQL + t)) * CDD;
    #pragma unroll
    for (int j = 0; j < 3; j++) {
      float cur = __bfloat162float(irow[ch[j]]);
      float a = bias[j] + w[j][0] * win[j][0] + w[j][1] * win[j][1]
                        + w[j][2] * win[j][2] + w[j][3] * cur;
      a = a / (1.f + expf(-a));
      orow[ch[j]] = __float2bfloat16(a);
      win[j][0] = win[j][1]; win[j][1] = win[j][2]; win[j][2] = cur;
    }
  }
}

// Phase 1 (MFMA): per (chunk, head, dir, batch): intra-chunk Y, chunk-state S, gamma, P_t
// dt/softplus/lambda from the f32 side-channel dtf.
__global__ __launch_bounds__(256) void chunk_p1(const bf16_t* __restrict__ xbc,
    const float* __restrict__ dtf, const float* __restrict__ dt_bias,
    const float* __restrict__ A_log,
    bf16_t* __restrict__ ybuf, float* __restrict__ Sbuf, float* __restrict__ gbuf,
    float* __restrict__ Pbuf, int layer) {
  int c = blockIdx.x, hd = blockIdx.y, b = blockIdx.z;
  int h = hd >> 1, d = hd & 1;
  int tid = threadIdx.x, lane = tid & 63, wid = tid >> 6;
  int rb = b * SEQL;
  __shared__ __align__(16) bf16_t Bs[QC][40];    // B[s][n]
  __shared__ __align__(16) bf16_t Cs[QC][40];    // C[t][n]
  __shared__ __align__(16) bf16_t Xt[QC][72];    // X^T[p][s]
  __shared__ __align__(16) bf16_t Ms[QC][72];    // M[t][s]
  __shared__ __align__(16) bf16_t Btw[DSs][72];  // (w.B)^T[n][s]
  __shared__ float lam[QC], dts[QC], wss[QC];

  for (int i = tid; i < QC * DSs; i += 256) {
    int s = i >> 5, n = i & 31;
    const bf16_t* row = xbc + ((size_t)(d * RT + rb + torig(d, c, s))) * CDD + DIi;
    Bs[s][n] = row[n];
    Cs[s][n] = row[DSs + n];
  }
  for (int i = tid; i < QC * HDD; i += 256) {
    int s = i >> 6, p = i & 63;
    Xt[p][s] = xbc[((size_t)(d * RT + rb + torig(d, c, s))) * CDD + h * HDD + p];
  }
  if (tid < QC) {  // wave 0: dt, then inclusive scan of log-decay
    int ro = rb + torig(d, c, tid);
    size_t rr = (size_t)d * RT + ro;
    float xv = dtf[rr * NHH + h] + dt_bias[(layer * 2 + d) * NHH + h];
    float dtv = (xv > 20.f) ? xv : log1pf(expf(xv));
    float Ah = -expf(A_log[(layer * 2 + d) * NHH + h]);
    float la = dtv * Ah;
    dts[tid] = dtv;
    #pragma unroll
    for (int o = 1; o < 64; o <<= 1) { float vv = __shfl_up(la, o); if (tid >= o) la += vv; }
    lam[tid] = la;
    float Pv = expf(la);
    Pbuf[rr * NHH + h] = Pv;
    float lq = __shfl(la, 63);
    wss[tid] = expf(lq - la) * dtv;
    if (tid == 63) gbuf[((b * NHH + h) * 2 + d) * NCH + c] = Pv;
  }
  __syncthreads();

  // G = C @ B^T ; M[t][s] = causal exp(lam_t-lam_s)*dt_s*G
  {
    short8 cf = *(const short8*)&Cs[wid * 16 + (lane & 15)][(lane >> 4) * 8];
    int sbase = lane & 15;
    #pragma unroll
    for (int sc = 0; sc < 4; sc++) {
      int s = sc * 16 + sbase;
      if (sc <= wid) {
        short8 bfr = *(const short8*)&Bs[s][(lane >> 4) * 8];
        f32x4 g = {};
        g = __builtin_amdgcn_mfma_f32_16x16x32_bf16(cf, bfr, g, 0, 0, 0);
        float ls = lam[s], dv = dts[s];
        #pragma unroll
        for (int j = 0; j < 4; j++) {
          int t = wid * 16 + (lane >> 4) * 4 + j;
          float m = (s <= t) ? expf(lam[t] - ls) * dv * g[j] : 0.f;
          Ms[t][s] = __float2bfloat16(m);
        }
      } else {
        #pragma unroll
        for (int j = 0; j < 4; j++) Ms[wid * 16 + (lane >> 4) * 4 + j][s] = __float2bfloat16(0.f);
      }
    }
  }
  // Btw[n][s] = wss[s] * B[s][n]
  for (int i = tid; i < DSs * QC; i += 256) {
    int n = i >> 6, s = i & 63;
    Btw[n][s] = __float2bfloat16(wss[s] * __bfloat162float(Bs[s][n]));
  }
  __syncthreads();

  // Y = M @ X : A=Ms[t][s], B=Xt[p][s]; wave wid owns t-strip
  {
    short8 ma0 = *(const short8*)&Ms[wid * 16 + (lane & 15)][(lane >> 4) * 8];
    short8 ma1 = *(const short8*)&Ms[wid * 16 + (lane & 15)][32 + (lane >> 4) * 8];
    #pragma unroll
    for (int pt = 0; pt < 4; pt++) {
      short8 xb0 = *(const short8*)&Xt[pt * 16 + (lane & 15)][(lane >> 4) * 8];
      short8 xb1 = *(const short8*)&Xt[pt * 16 + (lane & 15)][32 + (lane >> 4) * 8];
      f32x4 ya = {};
      ya = __builtin_amdgcn_mfma_f32_16x16x32_bf16(ma0, xb0, ya, 0, 0, 0);
      ya = __builtin_amdgcn_mfma_f32_16x16x32_bf16(ma1, xb1, ya, 0, 0, 0);
      int p = pt * 16 + (lane & 15);
      #pragma unroll
      for (int j = 0; j < 4; j++) {
        int t = wid * 16 + (lane >> 4) * 4 + j;
        ybuf[((size_t)(d * RT + rb + torig(d, c, t))) * DIi + h * HDD + p] = __float2bfloat16(ya[j]);
      }
    }
  }
  // S[p][n] = sum_s Xt[p][s] * Btw[n][s]; wave wid owns p-strip
  {
    short8 xa0 = *(const short8*)&Xt[wid * 16 + (lane & 15)][(lane >> 4) * 8];
    short8 xa1 = *(const short8*)&Xt[wid * 16 + (lane & 15)][32 + (lane >> 4) * 8];
    size_t base = ((size_t)((b * NHH + h) * 2 + d) * NCH + c) * 2048;
    #pragma unroll
    for (int nt = 0; nt < 2; nt++) {
      short8 bw0 = *(const short8*)&Btw[nt * 16 + (lane & 15)][(lane >> 4) * 8];
      short8 bw1 = *(const short8*)&Btw[nt * 16 + (lane & 15)][32 + (lane >> 4) * 8];
      f32x4 sa = {};
      sa = __builtin_amdgcn_mfma_f32_16x16x32_bf16(xa0, bw0, sa, 0, 0, 0);
      sa = __builtin_amdgcn_mfma_f32_16x16x32_bf16(xa1, bw1, sa, 0, 0, 0);
      int n = nt * 16 + (lane & 15);
      #pragma unroll
      for (int j = 0; j < 4; j++) {
        int p = wid * 16 + (lane >> 4) * 4 + j;
        Sbuf[base + (size_t)p * DSs + n] = sa[j];
      }
    }
  }
}

// Phase 2: sequential over 32 chunks; writes H_prev (state entering each chunk)
__global__ void chunk_p2(const float* __restrict__ Sbuf, const float* __restrict__ gbuf,
                         float* __restrict__ Hbuf) {
  int bhd = blockIdx.x;          // (b*8+h)*2+d
  int p = threadIdx.x;           // 64
  float H[DSs];
  #pragma unroll
  for (int n = 0; n < DSs; n++) H[n] = 0.f;
  const float* Sb = Sbuf + (size_t)bhd * NCH * 2048;
  float* Hb = Hbuf + (size_t)bhd * NCH * 2048;
  const float* gb = gbuf + bhd * NCH;
  for (int c = 0; c < NCH; c++) {
    #pragma unroll
    for (int n = 0; n < DSs; n++) Hb[(size_t)c * 2048 + p * DSs + n] = H[n];
    float g = gb[c];
    #pragma unroll
    for (int n = 0; n < DSs; n++) H[n] = g * H[n] + Sb[(size_t)c * 2048 + p * DSs + n];
  }
}

// Phase 3 (MFMA): Y += P_t * (C_t @ H_prev^T) + D * x
__global__ __launch_bounds__(256) void chunk_p3(const bf16_t* __restrict__ xbc,
    const float* __restrict__ Pbuf, const float* __restrict__ Hbuf,
    const float* __restrict__ Dvec, bf16_t* __restrict__ ybuf, int layer) {
  int c = blockIdx.x, hd = blockIdx.y, b = blockIdx.z;
  int h = hd >> 1, d = hd & 1;
  int tid = threadIdx.x, lane = tid & 63, wid = tid >> 6;
  int rb = b * SEQL;
  __shared__ __align__(16) bf16_t Cs[QC][40];    // C[t][n]
  __shared__ __align__(16) bf16_t Hs[HDD][40];   // H[p][n]
  __shared__ float Ps[QC];
  for (int i = tid; i < QC * DSs; i += 256) {
    int s = i >> 5, n = i & 31;
    Cs[s][n] = xbc[((size_t)(d * RT + rb + torig(d, c, s))) * CDD + DIi + DSs + n];
  }
  {
    size_t hb = ((size_t)((b * NHH + h) * 2 + d) * NCH + c) * 2048;
    for (int i = tid; i < HDD * DSs; i += 256) Hs[i >> 5][i & 31] = __float2bfloat16(Hbuf[hb + i]);
  }
  if (tid < QC) Ps[tid] = Pbuf[((size_t)(d * RT + rb + torig(d, c, tid))) * NHH + h];
  __syncthreads();
  float Dv = Dvec[(layer * 2 + d) * NHH + h];
  short8 ca = *(const short8*)&Cs[wid * 16 + (lane & 15)][(lane >> 4) * 8];
  #pragma unroll
  for (int pc = 0; pc < 4; pc++) {
    short8 hb = *(const short8*)&Hs[pc * 16 + (lane & 15)][(lane >> 4) * 8];
    f32x4 a = {};
    a = __builtin_amdgcn_mfma_f32_16x16x32_bf16(ca, hb, a, 0, 0, 0);
    int p = pc * 16 + (lane & 15);
    #pragma unroll
    for (int j = 0; j < 4; j++) {
      int t = wid * 16 + (lane >> 4) * 4 + j;
      size_t rr = (size_t)(d * RT + rb + torig(d, c, t));
      float xv = __bfloat162float(xbc[rr * CDD + h * HDD + p]);
      size_t yi = rr * DIi + h * HDD + p;
      float yv = __bfloat162float(ybuf[yi]);
      ybuf[yi] = __float2bfloat16(yv + Ps[t] * a[j] + Dv * xv);
    }
  }
}

// gate (silu(z)) + RMSNorm + gnorm, write bf16 into concatenated out-proj input
__global__ void gate_kernel(const bf16_t* __restrict__ zx, const bf16_t* __restrict__ ybuf,
                            const float* __restrict__ gnorm, bf16_t* __restrict__ ycat, int layer) {
  int r = blockIdx.x, d = blockIdx.y, lane = threadIdx.x;  // 64 threads
  const bf16_t* yrow = ybuf + ((size_t)(d * RT + r)) * DIi;
  const bf16_t* zrow = zx + (size_t)r * ZXT + d * ZXD;
  const float* gw = gnorm + (layer * 2 + d) * DIi;
  float g[8]; float ss = 0.f;
  #pragma unroll
  for (int j = 0; j < 8; j++) {
    int e = j * 64 + lane;
    float y = __bfloat162float(yrow[e]);
    float z = __bfloat162float(zrow[e]);
    float v = y * z / (1.f + expf(-z));
    g[j] = v; ss += v * v;
  }
  #pragma unroll
  for (int o = 32; o; o >>= 1) ss += __shfl_xor(ss, o);
  float sc = rsqrtf(ss * (1.f / DIi) + EPSV);
  #pragma unroll
  for (int j = 0; j < 8; j++) {
    int e = j * 64 + lane;
    ycat[(size_t)r * 1024 + d * DIi + e] = __float2bfloat16(g[j] * sc * gw[e]);
  }
}

extern "C" void kernel_launch(void* const* d_in, const int* in_sizes, int n_in,
                              void* d_out, int out_size, void* d_ws, size_t ws_size,
                              hipStream_t stream) {
  const float* x_in    = (const float*)d_in[0];
  const void*  maskp   = (const void*)d_in[1];
  const float* in_w    = (const float*)d_in[2];
  const float* conv_w  = (const float*)d_in[3];
  const float* conv_b  = (const float*)d_in[4];
  const float* dt_bias = (const float*)d_in[5];
  const float* A_log   = (const float*)d_in[6];
  const float* Dvec    = (const float*)d_in[7];
  const float* gnorm_w = (const float*)d_in[8];
  const float* out_w   = (const float*)d_in[9];
  const float* ln_w    = (const float*)d_in[10];
  const float* ln_b    = (const float*)d_in[11];

  char* ws = (char*)d_ws;
  size_t off = 0;
  auto alloc = [&](size_t bytes) -> void* {
    void* p = ws + off; off += (bytes + 255) & ~(size_t)255; return p;
  };
  float*  x_cur   = (float*)alloc((size_t)RT * DMm * 4);
  bf16_t* h_bf    = (bf16_t*)alloc((size_t)RT * DMm * 2);
  bf16_t* zx      = (bf16_t*)alloc((size_t)RT * ZXT * 2);
  bf16_t* xbc     = (bf16_t*)alloc((size_t)2 * RT * CDD * 2);
  float*  dtf     = (float*)alloc((size_t)2 * RT * NHH * 4);
  float*  Pbuf    = (float*)alloc((size_t)2 * RT * NHH * 4);
  bf16_t* ybuf    = (bf16_t*)alloc((size_t)2 * RT * DIi * 2);
  bf16_t* ycat    = (bf16_t*)alloc((size_t)RT * 1024 * 2);
  float*  Sbuf    = (float*)alloc((size_t)64 * NCH * 2048 * 4);
  float*  Hbuf    = (float*)alloc((size_t)64 * NCH * 2048 * 4);
  float*  gbuf    = (float*)alloc((size_t)64 * NCH * 4);
  bf16_t* inw_bf  = (bf16_t*)alloc((size_t)NLAY * ZXT * DMm * 2);
  bf16_t* wcat_bf = (bf16_t*)alloc((size_t)NLAY * DMm * 1024 * 2);
  int*    mflag   = (int*)alloc(256);

  hipMemcpyAsync(x_cur, x_in, (size_t)RT * DMm * 4, hipMemcpyDeviceToDevice, stream);
  detect_mask<<<1, 256, 0, stream>>>((const unsigned char*)maskp, mflag);
  cvt_weights<<<256, 256, 0, stream>>>(in_w, out_w, inw_bf, wcat_bf);

  for (int layer = 0; layer < NLAY; layer++) {
    ln_kernel<<<RT, 64, 0, stream>>>(x_cur, h_bf, ln_w, ln_b);
    gemm_k<0><<<dim3((ZXT + 63) / 64, RT / 64), 256, 0, stream>>>(
        h_bf, inw_bf + (size_t)layer * ZXT * DMm, nullptr, zx, dtf,
        RT, ZXT, DMm, ZXT, nullptr, mflag);
    conv_tile<<<dim3(SEQL / CTT, NB, 2), 192, 0, stream>>>(zx, conv_w, conv_b, xbc, layer);
    chunk_p1<<<dim3(NCH, 16, NB), 256, 0, stream>>>(xbc, dtf, dt_bias, A_log,
                                                    ybuf, Sbuf, gbuf, Pbuf, layer);
    chunk_p2<<<64, 64, 0, stream>>>(Sbuf, gbuf, Hbuf);
    chunk_p3<<<dim3(NCH, 16, NB), 256, 0, stream>>>(xbc, Pbuf, Hbuf, Dvec, ybuf, layer);
    gate_kernel<<<dim3(RT, 2), 64, 0, stream>>>(zx, ybuf, gnorm_w, ycat, layer);
    gemm_k<1><<<dim3(DMm / 64, RT / 64), 256, 0, stream>>>(
        ycat, wcat_bf + (size_t)layer * DMm * 1024, x_cur, nullptr, nullptr,
        RT, DMm, 1024, DMm, maskp, mflag);
  }
  final_ln<<<RT, 64, 0, stream>>>(x_cur, maskp, mflag, ln_w, ln_b, (float*)d_out);
}

// Round 5
// 313.309 us; speedup vs baseline: 1.8358x; 1.1006x over previous
//
#include <hip/hip_runtime.h>
#include <hip/hip_bf16.h>
#include <math.h>

#define SEQL 2048
#define NB 4
#define DMm 256
#define DIi 512
#define DSs 32
#define NHH 8
#define HDD 64
#define CDD 576
#define ZXD 1096
#define ZXT 2192
#define NPAD 2304
#define NLAY 2
#define QC 64
#define NCH 32
#define RT 8192
#define CTT 16
#define EPSV 1e-5f

typedef __hip_bfloat16 bf16_t;
using short8 = __attribute__((ext_vector_type(8))) short;
using f32x4  = __attribute__((ext_vector_type(4))) float;

__device__ __forceinline__ int torig(int d, int c, int s) {
  int v = c * QC + s;
  return d ? (SEQL - 1 - v) : v;
}

__device__ __forceinline__ int is_masked(const void* mask, const int* mflag, int r) {
  return (*mflag) ? (int)(((const unsigned char*)mask)[r] != 0)
                  : (int)(((const int*)mask)[r] != 0);
}

// mask dtype detection: int32 {0,1} has all bytes at pos%4!=0 equal to 0;
// bool8 has ~half nonzero. Reading RT bytes is in-bounds for both layouts.
__global__ void detect_mask(const unsigned char* __restrict__ m, int* __restrict__ flag) {
  __shared__ int any;
  if (threadIdx.x == 0) any = 0;
  __syncthreads();
  int a = 0;
  for (int i = threadIdx.x; i < RT; i += blockDim.x)
    if ((i & 3) && m[i]) a = 1;
  if (a) atomicOr(&any, 1);
  __syncthreads();
  if (threadIdx.x == 0) *flag = any;
}

// inw_bf: [l][NPAD=2304][256], rows >= 2192 zeroed (lets gemm_in stage without bounds checks)
__global__ void cvt_weights(const float* __restrict__ in_w, const float* __restrict__ out_w,
                            bf16_t* __restrict__ inw_bf, bf16_t* __restrict__ wcat_bf) {
  const int n1 = NLAY * NPAD * DMm;
  const int n2 = NLAY * DMm * 1024;
  for (int idx = blockIdx.x * blockDim.x + threadIdx.x; idx < n1 + n2; idx += gridDim.x * blockDim.x) {
    if (idx < n1) {
      int l = idx / (NPAD * DMm);
      int rem = idx % (NPAD * DMm);
      int r = rem / DMm, k = rem % DMm;
      inw_bf[idx] = __float2bfloat16(r < ZXT ? in_w[((size_t)l * ZXT + r) * DMm + k] : 0.f);
    } else {
      int j = idx - n1;                            // wcat: [l][d(256)][k(1024)], k = dir*512+e
      int l = j / (DMm * 1024);
      int rem = j % (DMm * 1024);
      int dd = rem >> 10, k = rem & 1023;
      int dir = k >> 9, e = k & 511;
      wcat_bf[j] = __float2bfloat16(out_w[((size_t)((l * 2 + dir) * DMm) + dd) * DIi + e]);
    }
  }
}

__global__ void ln_kernel(const float* __restrict__ x, bf16_t* __restrict__ h,
                          const float* __restrict__ lnw, const float* __restrict__ lnb) {
  int r = blockIdx.x, lane = threadIdx.x;   // 64 threads, 4 cols each
  float4 v = ((const float4*)(x + (size_t)r * DMm))[lane];
  float s = v.x + v.y + v.z + v.w;
  #pragma unroll
  for (int o = 32; o; o >>= 1) s += __shfl_xor(s, o);
  float mu = s * (1.f / DMm);
  float d0 = v.x - mu, d1 = v.y - mu, d2 = v.z - mu, d3 = v.w - mu;
  float q = d0*d0 + d1*d1 + d2*d2 + d3*d3;
  #pragma unroll
  for (int o = 32; o; o >>= 1) q += __shfl_xor(q, o);
  float rstd = rsqrtf(q * (1.f / DMm) + EPSV);
  float4 w  = ((const float4*)lnw)[lane];
  float4 bb = ((const float4*)lnb)[lane];
  union { bf16_t o4[4]; uint2 u; } out;
  out.o4[0] = __float2bfloat16(d0 * rstd * w.x + bb.x);
  out.o4[1] = __float2bfloat16(d1 * rstd * w.y + bb.y);
  out.o4[2] = __float2bfloat16(d2 * rstd * w.z + bb.z);
  out.o4[3] = __float2bfloat16(d3 * rstd * w.w + bb.w);
  ((uint2*)(h + (size_t)r * DMm))[lane] = out.u;
}

__global__ void final_ln(const float* __restrict__ x, const void* __restrict__ mask,
                         const int* __restrict__ mflag,
                         const float* __restrict__ lnw, const float* __restrict__ lnb,
                         float* __restrict__ out) {
  int r = blockIdx.x, lane = threadIdx.x;
  float4 v = ((const float4*)(x + (size_t)r * DMm))[lane];
  float s = v.x + v.y + v.z + v.w;
  #pragma unroll
  for (int o = 32; o; o >>= 1) s += __shfl_xor(s, o);
  float mu = s * (1.f / DMm);
  float d0 = v.x - mu, d1 = v.y - mu, d2 = v.z - mu, d3 = v.w - mu;
  float q = d0*d0 + d1*d1 + d2*d2 + d3*d3;
  #pragma unroll
  for (int o = 32; o; o >>= 1) q += __shfl_xor(q, o);
  float rstd = rsqrtf(q * (1.f / DMm) + EPSV);
  float4 w  = ((const float4*)lnw)[lane];
  float4 bb = ((const float4*)lnb)[lane];
  float4 o4;
  if (is_masked(mask, mflag, r)) { o4.x = o4.y = o4.z = o4.w = 0.f; }
  else {
    o4.x = d0 * rstd * w.x + bb.x; o4.y = d1 * rstd * w.y + bb.y;
    o4.z = d2 * rstd * w.z + bb.z; o4.w = d3 * rstd * w.w + bb.w;
  }
  ((float4*)(out + (size_t)r * DMm))[lane] = o4;
}

// In-projection GEMM: 128x128 tile, BK=64, reg-staged padded LDS (stride 72 bf16 = 144B,
// 2-way bank aliasing = free). A[RT][256] bf16, Bw[NPAD][256] bf16 (pad rows zero).
// Writes bf16 zx (col<ZXT) + f32 dt side-channel (cols 1088-1095 / 2184-2191).
__global__ __launch_bounds__(256) void gemm_in(const bf16_t* __restrict__ A,
    const bf16_t* __restrict__ Bw, bf16_t* __restrict__ zx, float* __restrict__ dtf) {
  __shared__ __align__(16) bf16_t As[128][72];
  __shared__ __align__(16) bf16_t Bs[128][72];
  int n0 = blockIdx.x * 128, m0 = blockIdx.y * 128;
  int tid = threadIdx.x, lane = tid & 63, wid = tid >> 6;
  int wm = wid >> 1, wn = wid & 1;
  f32x4 acc[4][4] = {};
  int sr = tid >> 1, sh = (tid & 1) * 32;
  for (int k0 = 0; k0 < DMm; k0 += 64) {
    #pragma unroll
    for (int i = 0; i < 4; i++) {
      *(short8*)&As[sr][sh + i * 8] = *(const short8*)(A + (size_t)(m0 + sr) * DMm + k0 + sh + i * 8);
      *(short8*)&Bs[sr][sh + i * 8] = *(const short8*)(Bw + (size_t)(n0 + sr) * DMm + k0 + sh + i * 8);
    }
    __syncthreads();
    #pragma unroll
    for (int kk = 0; kk < 2; kk++) {
      short8 af[4], bf[4];
      #pragma unroll
      for (int mi = 0; mi < 4; mi++)
        af[mi] = *(const short8*)&As[wm * 64 + mi * 16 + (lane & 15)][kk * 32 + (lane >> 4) * 8];
      #pragma unroll
      for (int ni = 0; ni < 4; ni++)
        bf[ni] = *(const short8*)&Bs[wn * 64 + ni * 16 + (lane & 15)][kk * 32 + (lane >> 4) * 8];
      #pragma unroll
      for (int mi = 0; mi < 4; mi++)
        #pragma unroll
        for (int ni = 0; ni < 4; ni++)
          acc[mi][ni] = __builtin_amdgcn_mfma_f32_16x16x32_bf16(af[mi], bf[ni], acc[mi][ni], 0, 0, 0);
    }
    __syncthreads();
  }
  #pragma unroll
  for (int mi = 0; mi < 4; mi++) {
    #pragma unroll
    for (int ni = 0; ni < 4; ni++) {
      int col = n0 + wn * 64 + ni * 16 + (lane & 15);
      if (col < ZXT) {
        #pragma unroll
        for (int j = 0; j < 4; j++) {
          int row = m0 + wm * 64 + mi * 16 + (lane >> 4) * 4 + j;
          float v = acc[mi][ni][j];
          zx[(size_t)row * ZXT + col] = __float2bfloat16(v);
          if (col >= 1088 && col < 1096)
            dtf[(size_t)row * NHH + (col - 1088)] = v;
          else if (col >= 2184)
            dtf[((size_t)RT + row) * NHH + (col - 2184)] = v;
        }
      }
    }
  }
}

// Out-projection GEMM (64x64): C = A(MxK) * Bw(NxK)^T, masked += into f32 C.
__global__ __launch_bounds__(256) void gemm_out(const bf16_t* __restrict__ A, const bf16_t* __restrict__ Bw,
    float* __restrict__ C, int M, int N, int K, int ldc,
    const void* __restrict__ mask, const int* __restrict__ mflag) {
  __shared__ bf16_t As[64][40];
  __shared__ bf16_t Bs[64][40];
  int n0 = blockIdx.x * 64, m0 = blockIdx.y * 64;
  int tid = threadIdx.x, lane = tid & 63, wid = tid >> 6;
  f32x4 acc[4] = {};
  int sr = tid >> 2, sk = (tid & 3) * 8;
  for (int k0 = 0; k0 < K; k0 += 32) {
    short8 av = *(const short8*)(A + (size_t)(m0 + sr) * K + k0 + sk);
    *(short8*)&As[sr][sk] = av;
    short8 bv = *(const short8*)(Bw + (size_t)(n0 + sr) * K + k0 + sk);
    *(short8*)&Bs[sr][sk] = bv;
    __syncthreads();
    short8 af = *(const short8*)&As[wid * 16 + (lane & 15)][(lane >> 4) * 8];
    #pragma unroll
    for (int nt = 0; nt < 4; nt++) {
      short8 bf = *(const short8*)&Bs[nt * 16 + (lane & 15)][(lane >> 4) * 8];
      acc[nt] = __builtin_amdgcn_mfma_f32_16x16x32_bf16(af, bf, acc[nt], 0, 0, 0);
    }
    __syncthreads();
  }
  #pragma unroll
  for (int nt = 0; nt < 4; nt++) {
    int col = n0 + nt * 16 + (lane & 15);
    #pragma unroll
    for (int j = 0; j < 4; j++) {
      int row = m0 + wid * 16 + (lane >> 4) * 4 + j;
      if (!is_masked(mask, mflag, row)) C[(size_t)row * ldc + col] += acc[nt][j];
    }
  }
}

// Time-tiled depthwise conv + silu on bf16 zx.
__global__ __launch_bounds__(192) void conv_tile(const bf16_t* __restrict__ zx,
    const float* __restrict__ conv_w, const float* __restrict__ conv_b,
    bf16_t* __restrict__ xbc, int layer) {
  int tile = blockIdx.x, b = blockIdx.y, d = blockIdx.z;
  int v0 = tile * CTT;
  int tid = threadIdx.x;
  const float* cwp = conv_w + (size_t)((layer * 2 + d) * CDD) * 4;
  const float* cbp = conv_b + (layer * 2 + d) * CDD;
  float w[3][4]; float bias[3]; int ch[3];
  #pragma unroll
  for (int j = 0; j < 3; j++) {
    ch[j] = tid + 192 * j;
    bias[j] = cbp[ch[j]];
    #pragma unroll
    for (int i = 0; i < 4; i++) w[j][i] = cwp[ch[j] * 4 + i];
  }
  const bf16_t* zbase = zx + (size_t)b * SEQL * ZXT + d * ZXD + DIi;
  float win[3][3];
  #pragma unroll
  for (int k = 0; k < 3; k++) {
    int v = v0 - 3 + k;
    int t = d ? (SEQL - 1 - v) : v;
    bool ok = (v >= 0);
    #pragma unroll
    for (int j = 0; j < 3; j++)
      win[j][k] = ok ? __bfloat162float(zbase[(size_t)t * ZXT + ch[j]]) : 0.f;
  }
  for (int it = 0; it < CTT; it++) {
    int v = v0 + it;
    int t = d ? (SEQL - 1 - v) : v;
    const bf16_t* irow = zbase + (size_t)t * ZXT;
    bf16_t* orow = xbc + ((size_t)(d * RT + b * SEQL + t)) * CDD;
    #pragma unroll
    for (int j = 0; j < 3; j++) {
      float cur = __bfloat162float(irow[ch[j]]);
      float a = bias[j] + w[j][0] * win[j][0] + w[j][1] * win[j][1]
                        + w[j][2] * win[j][2] + w[j][3] * cur;
      a = a / (1.f + expf(-a));
      orow[ch[j]] = __float2bfloat16(a);
      win[j][0] = win[j][1]; win[j][1] = win[j][2]; win[j][2] = cur;
    }
  }
}

// Phase 1 (MFMA): intra-chunk Y, chunk-state S, log-gamma, P_t
__global__ __launch_bounds__(256) void chunk_p1(const bf16_t* __restrict__ xbc,
    const float* __restrict__ dtf, const float* __restrict__ dt_bias,
    const float* __restrict__ A_log,
    bf16_t* __restrict__ ybuf, float* __restrict__ Sbuf, float* __restrict__ lgbuf,
    float* __restrict__ Pbuf, int layer) {
  int c = blockIdx.x, hd = blockIdx.y, b = blockIdx.z;
  int h = hd >> 1, d = hd & 1;
  int tid = threadIdx.x, lane = tid & 63, wid = tid >> 6;
  int rb = b * SEQL;
  __shared__ __align__(16) bf16_t Bs[QC][40];    // B[s][n]
  __shared__ __align__(16) bf16_t Cs[QC][40];    // C[t][n]
  __shared__ __align__(16) bf16_t Xt[QC][72];    // X^T[p][s]
  __shared__ __align__(16) bf16_t Ms[QC][72];    // M[t][s]
  __shared__ __align__(16) bf16_t Btw[DSs][72];  // (w.B)^T[n][s]
  __shared__ float lam[QC], dts[QC], wss[QC];

  for (int i = tid; i < QC * DSs; i += 256) {
    int s = i >> 5, n = i & 31;
    const bf16_t* row = xbc + ((size_t)(d * RT + rb + torig(d, c, s))) * CDD + DIi;
    Bs[s][n] = row[n];
    Cs[s][n] = row[DSs + n];
  }
  for (int i = tid; i < QC * HDD; i += 256) {
    int s = i >> 6, p = i & 63;
    Xt[p][s] = xbc[((size_t)(d * RT + rb + torig(d, c, s))) * CDD + h * HDD + p];
  }
  if (tid < QC) {  // wave 0: dt, then inclusive scan of log-decay
    int ro = rb + torig(d, c, tid);
    size_t rr = (size_t)d * RT + ro;
    float xv = dtf[rr * NHH + h] + dt_bias[(layer * 2 + d) * NHH + h];
    float dtv = (xv > 20.f) ? xv : log1pf(expf(xv));
    float Ah = -expf(A_log[(layer * 2 + d) * NHH + h]);
    float la = dtv * Ah;
    dts[tid] = dtv;
    #pragma unroll
    for (int o = 1; o < 64; o <<= 1) { float vv = __shfl_up(la, o); if (tid >= o) la += vv; }
    lam[tid] = la;
    Pbuf[rr * NHH + h] = expf(la);
    float lq = __shfl(la, 63);
    wss[tid] = expf(lq - la) * dtv;
    if (tid == 63) lgbuf[((b * NHH + h) * 2 + d) * NCH + c] = la;  // log-gamma of chunk
  }
  __syncthreads();

  // G = C @ B^T ; M[t][s] = causal exp(lam_t-lam_s)*dt_s*G
  {
    short8 cf = *(const short8*)&Cs[wid * 16 + (lane & 15)][(lane >> 4) * 8];
    int sbase = lane & 15;
    #pragma unroll
    for (int sc = 0; sc < 4; sc++) {
      int s = sc * 16 + sbase;
      if (sc <= wid) {
        short8 bfr = *(const short8*)&Bs[s][(lane >> 4) * 8];
        f32x4 g = {};
        g = __builtin_amdgcn_mfma_f32_16x16x32_bf16(cf, bfr, g, 0, 0, 0);
        float ls = lam[s], dv = dts[s];
        #pragma unroll
        for (int j = 0; j < 4; j++) {
          int t = wid * 16 + (lane >> 4) * 4 + j;
          float m = (s <= t) ? expf(lam[t] - ls) * dv * g[j] : 0.f;
          Ms[t][s] = __float2bfloat16(m);
        }
      } else {
        #pragma unroll
        for (int j = 0; j < 4; j++) Ms[wid * 16 + (lane >> 4) * 4 + j][s] = __float2bfloat16(0.f);
      }
    }
  }
  // Btw[n][s] = wss[s] * B[s][n]
  for (int i = tid; i < DSs * QC; i += 256) {
    int n = i >> 6, s = i & 63;
    Btw[n][s] = __float2bfloat16(wss[s] * __bfloat162float(Bs[s][n]));
  }
  __syncthreads();

  // Y = M @ X : A=Ms[t][s], B=Xt[p][s]; wave wid owns t-strip
  {
    short8 ma0 = *(const short8*)&Ms[wid * 16 + (lane & 15)][(lane >> 4) * 8];
    short8 ma1 = *(const short8*)&Ms[wid * 16 + (lane & 15)][32 + (lane >> 4) * 8];
    #pragma unroll
    for (int pt = 0; pt < 4; pt++) {
      short8 xb0 = *(const short8*)&Xt[pt * 16 + (lane & 15)][(lane >> 4) * 8];
      short8 xb1 = *(const short8*)&Xt[pt * 16 + (lane & 15)][32 + (lane >> 4) * 8];
      f32x4 ya = {};
      ya = __builtin_amdgcn_mfma_f32_16x16x32_bf16(ma0, xb0, ya, 0, 0, 0);
      ya = __builtin_amdgcn_mfma_f32_16x16x32_bf16(ma1, xb1, ya, 0, 0, 0);
      int p = pt * 16 + (lane & 15);
      #pragma unroll
      for (int j = 0; j < 4; j++) {
        int t = wid * 16 + (lane >> 4) * 4 + j;
        ybuf[((size_t)(d * RT + rb + torig(d, c, t))) * DIi + h * HDD + p] = __float2bfloat16(ya[j]);
      }
    }
  }
  // S[p][n] = sum_s Xt[p][s] * Btw[n][s]; wave wid owns p-strip
  {
    short8 xa0 = *(const short8*)&Xt[wid * 16 + (lane & 15)][(lane >> 4) * 8];
    short8 xa1 = *(const short8*)&Xt[wid * 16 + (lane & 15)][32 + (lane >> 4) * 8];
    size_t base = ((size_t)((b * NHH + h) * 2 + d) * NCH + c) * 2048;
    #pragma unroll
    for (int nt = 0; nt < 2; nt++) {
      short8 bw0 = *(const short8*)&Btw[nt * 16 + (lane & 15)][(lane >> 4) * 8];
      short8 bw1 = *(const short8*)&Btw[nt * 16 + (lane & 15)][32 + (lane >> 4) * 8];
      f32x4 sa = {};
      sa = __builtin_amdgcn_mfma_f32_16x16x32_bf16(xa0, bw0, sa, 0, 0, 0);
      sa = __builtin_amdgcn_mfma_f32_16x16x32_bf16(xa1, bw1, sa, 0, 0, 0);
      int n = nt * 16 + (lane & 15);
      #pragma unroll
      for (int j = 0; j < 4; j++) {
        int p = wid * 16 + (lane >> 4) * 4 + j;
        Sbuf[base + (size_t)p * DSs + n] = sa[j];
      }
    }
  }
}

// Phase 2 (parallel): H_c = sum_{c'<c} exp(cum[c-1]-cum[c']) * S_{c'} — a 32x32
// lower-triangular matmul over chunk index. Grid (64 bhd, 8 colblk) x 256 thr.
__global__ __launch_bounds__(256) void chunk_p2b(const float* __restrict__ Sbuf,
    const float* __restrict__ lgbuf, bf16_t* __restrict__ Hbuf) {
  int bhd = blockIdx.x, cb = blockIdx.y;
  int tid = threadIdx.x;
  __shared__ float W[NCH][NCH + 1];
  __shared__ float cum[NCH];
  if (tid < NCH) {
    float la = lgbuf[bhd * NCH + tid];
    #pragma unroll
    for (int o = 1; o < NCH; o <<= 1) { float v = __shfl_up(la, o); if (tid >= o) la += v; }
    cum[tid] = la;
  }
  __syncthreads();
  for (int i = tid; i < NCH * NCH; i += 256) {
    int c = i >> 5, cp = i & 31;
    W[c][cp] = (cp < c) ? expf(cum[c - 1] - cum[cp]) : 0.f;
  }
  __syncthreads();
  int j = cb * 256 + tid;
  const float* Sb = Sbuf + (size_t)bhd * NCH * 2048;
  bf16_t* Hb = Hbuf + (size_t)bhd * NCH * 2048;
  float H[NCH];
  #pragma unroll
  for (int c = 0; c < NCH; c++) H[c] = 0.f;
  for (int cp = 0; cp < NCH; cp++) {
    float s = Sb[(size_t)cp * 2048 + j];
    #pragma unroll
    for (int c = 0; c < NCH; c++) H[c] += W[c][cp] * s;
  }
  #pragma unroll
  for (int c = 0; c < NCH; c++) Hb[(size_t)c * 2048 + j] = __float2bfloat16(H[c]);
}

// Phase 3 (MFMA): Y += P_t * (C_t @ H_prev^T) + D * x
__global__ __launch_bounds__(256) void chunk_p3(const bf16_t* __restrict__ xbc,
    const float* __restrict__ Pbuf, const bf16_t* __restrict__ Hbuf,
    const float* __restrict__ Dvec, bf16_t* __restrict__ ybuf, int layer) {
  int c = blockIdx.x, hd = blockIdx.y, b = blockIdx.z;
  int h = hd >> 1, d = hd & 1;
  int tid = threadIdx.x, lane = tid & 63, wid = tid >> 6;
  int rb = b * SEQL;
  __shared__ __align__(16) bf16_t Cs[QC][40];    // C[t][n]
  __shared__ __align__(16) bf16_t Hs[HDD][40];   // H[p][n]
  __shared__ float Ps[QC];
  for (int i = tid; i < QC * DSs; i += 256) {
    int s = i >> 5, n = i & 31;
    Cs[s][n] = xbc[((size_t)(d * RT + rb + torig(d, c, s))) * CDD + DIi + DSs + n];
  }
  {
    size_t hb = ((size_t)((b * NHH + h) * 2 + d) * NCH + c) * 2048;
    for (int i = tid; i < HDD * DSs; i += 256) Hs[i >> 5][i & 31] = Hbuf[hb + i];
  }
  if (tid < QC) Ps[tid] = Pbuf[((size_t)(d * RT + rb + torig(d, c, tid))) * NHH + h];
  __syncthreads();
  float Dv = Dvec[(layer * 2 + d) * NHH + h];
  short8 ca = *(const short8*)&Cs[wid * 16 + (lane & 15)][(lane >> 4) * 8];
  #pragma unroll
  for (int pc = 0; pc < 4; pc++) {
    short8 hb = *(const short8*)&Hs[pc * 16 + (lane & 15)][(lane >> 4) * 8];
    f32x4 a = {};
    a = __builtin_amdgcn_mfma_f32_16x16x32_bf16(ca, hb, a, 0, 0, 0);
    int p = pc * 16 + (lane & 15);
    #pragma unroll
    for (int j = 0; j < 4; j++) {
      int t = wid * 16 + (lane >> 4) * 4 + j;
      size_t rr = (size_t)(d * RT + rb + torig(d, c, t));
      float xv = __bfloat162float(xbc[rr * CDD + h * HDD + p]);
      size_t yi = rr * DIi + h * HDD + p;
      float yv = __bfloat162float(ybuf[yi]);
      ybuf[yi] = __float2bfloat16(yv + Ps[t] * a[j] + Dv * xv);
    }
  }
}

// gate (silu(z)) + RMSNorm + gnorm, write bf16 into concatenated out-proj input
__global__ void gate_kernel(const bf16_t* __restrict__ zx, const bf16_t* __restrict__ ybuf,
                            const float* __restrict__ gnorm, bf16_t* __restrict__ ycat, int layer) {
  int r = blockIdx.x, d = blockIdx.y, lane = threadIdx.x;  // 64 threads
  const bf16_t* yrow = ybuf + ((size_t)(d * RT + r)) * DIi;
  const bf16_t* zrow = zx + (size_t)r * ZXT + d * ZXD;
  const float* gw = gnorm + (layer * 2 + d) * DIi;
  float g[8]; float ss = 0.f;
  #pragma unroll
  for (int j = 0; j < 8; j++) {
    int e = j * 64 + lane;
    float y = __bfloat162float(yrow[e]);
    float z = __bfloat162float(zrow[e]);
    float v = y * z / (1.f + expf(-z));
    g[j] = v; ss += v * v;
  }
  #pragma unroll
  for (int o = 32; o; o >>= 1) ss += __shfl_xor(ss, o);
  float sc = rsqrtf(ss * (1.f / DIi) + EPSV);
  #pragma unroll
  for (int j = 0; j < 8; j++) {
    int e = j * 64 + lane;
    ycat[(size_t)r * 1024 + d * DIi + e] = __float2bfloat16(g[j] * sc * gw[e]);
  }
}

extern "C" void kernel_launch(void* const* d_in, const int* in_sizes, int n_in,
                              void* d_out, int out_size, void* d_ws, size_t ws_size,
                              hipStream_t stream) {
  const float* x_in    = (const float*)d_in[0];
  const void*  maskp   = (const void*)d_in[1];
  const float* in_w    = (const float*)d_in[2];
  const float* conv_w  = (const float*)d_in[3];
  const float* conv_b  = (const float*)d_in[4];
  const float* dt_bias = (const float*)d_in[5];
  const float* A_log   = (const float*)d_in[6];
  const float* Dvec    = (const float*)d_in[7];
  const float* gnorm_w = (const float*)d_in[8];
  const float* out_w   = (const float*)d_in[9];
  const float* ln_w    = (const float*)d_in[10];
  const float* ln_b    = (const float*)d_in[11];

  char* ws = (char*)d_ws;
  size_t off = 0;
  auto alloc = [&](size_t bytes) -> void* {
    void* p = ws + off; off += (bytes + 255) & ~(size_t)255; return p;
  };
  float*  x_cur   = (float*)alloc((size_t)RT * DMm * 4);
  bf16_t* h_bf    = (bf16_t*)alloc((size_t)RT * DMm * 2);
  bf16_t* zx      = (bf16_t*)alloc((size_t)RT * ZXT * 2);
  bf16_t* xbc     = (bf16_t*)alloc((size_t)2 * RT * CDD * 2);
  float*  dtf     = (float*)alloc((size_t)2 * RT * NHH * 4);
  float*  Pbuf    = (float*)alloc((size_t)2 * RT * NHH * 4);
  bf16_t* ybuf    = (bf16_t*)alloc((size_t)2 * RT * DIi * 2);
  bf16_t* ycat    = (bf16_t*)alloc((size_t)RT * 1024 * 2);
  float*  Sbuf    = (float*)alloc((size_t)64 * NCH * 2048 * 4);
  bf16_t* Hbuf    = (bf16_t*)alloc((size_t)64 * NCH * 2048 * 2);
  float*  lgbuf   = (float*)alloc((size_t)64 * NCH * 4);
  bf16_t* inw_bf  = (bf16_t*)alloc((size_t)NLAY * NPAD * DMm * 2);
  bf16_t* wcat_bf = (bf16_t*)alloc((size_t)NLAY * DMm * 1024 * 2);
  int*    mflag   = (int*)alloc(256);

  hipMemcpyAsync(x_cur, x_in, (size_t)RT * DMm * 4, hipMemcpyDeviceToDevice, stream);
  detect_mask<<<1, 256, 0, stream>>>((const unsigned char*)maskp, mflag);
  cvt_weights<<<256, 256, 0, stream>>>(in_w, out_w, inw_bf, wcat_bf);

  for (int layer = 0; layer < NLAY; layer++) {
    ln_kernel<<<RT, 64, 0, stream>>>(x_cur, h_bf, ln_w, ln_b);
    gemm_in<<<dim3(NPAD / 128, RT / 128), 256, 0, stream>>>(
        h_bf, inw_bf + (size_t)layer * NPAD * DMm, zx, dtf);
    conv_tile<<<dim3(SEQL / CTT, NB, 2), 192, 0, stream>>>(zx, conv_w, conv_b, xbc, layer);
    chunk_p1<<<dim3(NCH, 16, NB), 256, 0, stream>>>(xbc, dtf, dt_bias, A_log,
                                                    ybuf, Sbuf, lgbuf, Pbuf, layer);
    chunk_p2b<<<dim3(64, 8), 256, 0, stream>>>(Sbuf, lgbuf, Hbuf);
    chunk_p3<<<dim3(NCH, 16, NB), 256, 0, stream>>>(xbc, Pbuf, Hbuf, Dvec, ybuf, layer);
    gate_kernel<<<dim3(RT, 2), 64, 0, stream>>>(zx, ybuf, gnorm_w, ycat, layer);
    gemm_out<<<dim3(DMm / 64, RT / 64), 256, 0, stream>>>(
        ycat, wcat_bf + (size_t)layer * DMm * 1024, x_cur,
        RT, DMm, 1024, DMm, maskp, mflag);
  }
  final_ln<<<RT, 64, 0, stream>>>(x_cur, maskp, mflag, ln_w, ln_b, (float*)d_out);
}

// Round 7
// 292.689 us; speedup vs baseline: 1.9651x; 1.0704x over previous
//
#include <hip/hip_runtime.h>
#include <hip/hip_bf16.h>
#include <math.h>

#define SEQL 2048
#define NB 4
#define DMm 256
#define DIi 512
#define DSs 32
#define NHH 8
#define HDD 64
#define CDD 576
#define ZXD 1096
#define ZXT 2192
#define NPAD 2304
#define NLAY 2
#define QC 64
#define NCH 32
#define RT 8192
#define CTT 16
#define EPSV 1e-5f

typedef __hip_bfloat16 bf16_t;
using short8 = __attribute__((ext_vector_type(8))) short;
using f32x4  = __attribute__((ext_vector_type(4))) float;

__device__ __forceinline__ float bf16bits2f(short u) {
  union { unsigned int i; float f; } v;
  v.i = ((unsigned int)(unsigned short)u) << 16;
  return v.f;
}

__device__ __forceinline__ int torig(int d, int c, int s) {
  int v = c * QC + s;
  return d ? (SEQL - 1 - v) : v;
}

__device__ __forceinline__ int is_masked(const void* mask, const int* mflag, int r) {
  return (*mflag) ? (int)(((const unsigned char*)mask)[r] != 0)
                  : (int)(((const int*)mask)[r] != 0);
}

// mask dtype detection: int32 {0,1} has all bytes at pos%4!=0 equal to 0;
// bool8 has ~half nonzero. Reading RT bytes is in-bounds for both layouts.
__global__ void detect_mask(const unsigned char* __restrict__ m, int* __restrict__ flag) {
  __shared__ int any;
  if (threadIdx.x == 0) any = 0;
  __syncthreads();
  int a = 0;
  for (int i = threadIdx.x; i < RT; i += blockDim.x)
    if ((i & 3) && m[i]) a = 1;
  if (a) atomicOr(&any, 1);
  __syncthreads();
  if (threadIdx.x == 0) *flag = any;
}

// inw_bf: [l][NPAD=2304][256], rows >= 2192 zeroed (lets gemm_in stage without bounds checks)
__global__ void cvt_weights(const float* __restrict__ in_w, const float* __restrict__ out_w,
                            bf16_t* __restrict__ inw_bf, bf16_t* __restrict__ wcat_bf) {
  const int n1 = NLAY * NPAD * DMm;
  const int n2 = NLAY * DMm * 1024;
  for (int idx = blockIdx.x * blockDim.x + threadIdx.x; idx < n1 + n2; idx += gridDim.x * blockDim.x) {
    if (idx < n1) {
      int l = idx / (NPAD * DMm);
      int rem = idx % (NPAD * DMm);
      int r = rem / DMm, k = rem % DMm;
      inw_bf[idx] = __float2bfloat16(r < ZXT ? in_w[((size_t)l * ZXT + r) * DMm + k] : 0.f);
    } else {
      int j = idx - n1;                            // wcat: [l][d(256)][k(1024)], k = dir*512+e
      int l = j / (DMm * 1024);
      int rem = j % (DMm * 1024);
      int dd = rem >> 10, k = rem & 1023;
      int dir = k >> 9, e = k & 511;
      wcat_bf[j] = __float2bfloat16(out_w[((size_t)((l * 2 + dir) * DMm) + dd) * DIi + e]);
    }
  }
}

__global__ void ln_kernel(const float* __restrict__ x, bf16_t* __restrict__ h,
                          const float* __restrict__ lnw, const float* __restrict__ lnb) {
  int r = blockIdx.x, lane = threadIdx.x;   // 64 threads, 4 cols each
  float4 v = ((const float4*)(x + (size_t)r * DMm))[lane];
  float s = v.x + v.y + v.z + v.w;
  #pragma unroll
  for (int o = 32; o; o >>= 1) s += __shfl_xor(s, o);
  float mu = s * (1.f / DMm);
  float d0 = v.x - mu, d1 = v.y - mu, d2 = v.z - mu, d3 = v.w - mu;
  float q = d0*d0 + d1*d1 + d2*d2 + d3*d3;
  #pragma unroll
  for (int o = 32; o; o >>= 1) q += __shfl_xor(q, o);
  float rstd = rsqrtf(q * (1.f / DMm) + EPSV);
  float4 w  = ((const float4*)lnw)[lane];
  float4 bb = ((const float4*)lnb)[lane];
  union { bf16_t o4[4]; uint2 u; } out;
  out.o4[0] = __float2bfloat16(d0 * rstd * w.x + bb.x);
  out.o4[1] = __float2bfloat16(d1 * rstd * w.y + bb.y);
  out.o4[2] = __float2bfloat16(d2 * rstd * w.z + bb.z);
  out.o4[3] = __float2bfloat16(d3 * rstd * w.w + bb.w);
  ((uint2*)(h + (size_t)r * DMm))[lane] = out.u;
}

__global__ void final_ln(const float* __restrict__ x, const void* __restrict__ mask,
                         const int* __restrict__ mflag,
                         const float* __restrict__ lnw, const float* __restrict__ lnb,
                         float* __restrict__ out) {
  int r = blockIdx.x, lane = threadIdx.x;
  float4 v = ((const float4*)(x + (size_t)r * DMm))[lane];
  float s = v.x + v.y + v.z + v.w;
  #pragma unroll
  for (int o = 32; o; o >>= 1) s += __shfl_xor(s, o);
  float mu = s * (1.f / DMm);
  float d0 = v.x - mu, d1 = v.y - mu, d2 = v.z - mu, d3 = v.w - mu;
  float q = d0*d0 + d1*d1 + d2*d2 + d3*d3;
  #pragma unroll
  for (int o = 32; o; o >>= 1) q += __shfl_xor(q, o);
  float rstd = rsqrtf(q * (1.f / DMm) + EPSV);
  float4 w  = ((const float4*)lnw)[lane];
  float4 bb = ((const float4*)lnb)[lane];
  float4 o4;
  if (is_masked(mask, mflag, r)) { o4.x = o4.y = o4.z = o4.w = 0.f; }
  else {
    o4.x = d0 * rstd * w.x + bb.x; o4.y = d1 * rstd * w.y + bb.y;
    o4.z = d2 * rstd * w.z + bb.z; o4.w = d3 * rstd * w.w + bb.w;
  }
  ((float4*)(out + (size_t)r * DMm))[lane] = o4;
}

// In-projection GEMM: 128x128 tile, BK=64, reg-staged padded LDS (stride 72 bf16 = 144B,
// 2-way bank aliasing = free). Writes bf16 zx + f32 dt side-channel.
__global__ __launch_bounds__(256) void gemm_in(const bf16_t* __restrict__ A,
    const bf16_t* __restrict__ Bw, bf16_t* __restrict__ zx, float* __restrict__ dtf) {
  __shared__ __align__(16) bf16_t As[128][72];
  __shared__ __align__(16) bf16_t Bs[128][72];
  int n0 = blockIdx.x * 128, m0 = blockIdx.y * 128;
  int tid = threadIdx.x, lane = tid & 63, wid = tid >> 6;
  int wm = wid >> 1, wn = wid & 1;
  f32x4 acc[4][4] = {};
  int sr = tid >> 1, sh = (tid & 1) * 32;
  for (int k0 = 0; k0 < DMm; k0 += 64) {
    #pragma unroll
    for (int i = 0; i < 4; i++) {
      *(short8*)&As[sr][sh + i * 8] = *(const short8*)(A + (size_t)(m0 + sr) * DMm + k0 + sh + i * 8);
      *(short8*)&Bs[sr][sh + i * 8] = *(const short8*)(Bw + (size_t)(n0 + sr) * DMm + k0 + sh + i * 8);
    }
    __syncthreads();
    #pragma unroll
    for (int kk = 0; kk < 2; kk++) {
      short8 af[4], bf[4];
      #pragma unroll
      for (int mi = 0; mi < 4; mi++)
        af[mi] = *(const short8*)&As[wm * 64 + mi * 16 + (lane & 15)][kk * 32 + (lane >> 4) * 8];
      #pragma unroll
      for (int ni = 0; ni < 4; ni++)
        bf[ni] = *(const short8*)&Bs[wn * 64 + ni * 16 + (lane & 15)][kk * 32 + (lane >> 4) * 8];
      #pragma unroll
      for (int mi = 0; mi < 4; mi++)
        #pragma unroll
        for (int ni = 0; ni < 4; ni++)
          acc[mi][ni] = __builtin_amdgcn_mfma_f32_16x16x32_bf16(af[mi], bf[ni], acc[mi][ni], 0, 0, 0);
    }
    __syncthreads();
  }
  #pragma unroll
  for (int mi = 0; mi < 4; mi++) {
    #pragma unroll
    for (int ni = 0; ni < 4; ni++) {
      int col = n0 + wn * 64 + ni * 16 + (lane & 15);
      if (col < ZXT) {
        #pragma unroll
        for (int j = 0; j < 4; j++) {
          int row = m0 + wm * 64 + mi * 16 + (lane >> 4) * 4 + j;
          float v = acc[mi][ni][j];
          zx[(size_t)row * ZXT + col] = __float2bfloat16(v);
          if (col >= 1088 && col < 1096)
            dtf[(size_t)row * NHH + (col - 1088)] = v;
          else if (col >= 2184)
            dtf[((size_t)RT + row) * NHH + (col - 2184)] = v;
        }
      }
    }
  }
}

// Out-projection GEMM (64x64): C = A(MxK) * Bw(NxK)^T, masked += into f32 C.
__global__ __launch_bounds__(256) void gemm_out(const bf16_t* __restrict__ A, const bf16_t* __restrict__ Bw,
    float* __restrict__ C, int M, int N, int K, int ldc,
    const void* __restrict__ mask, const int* __restrict__ mflag) {
  __shared__ bf16_t As[64][40];
  __shared__ bf16_t Bs[64][40];
  int n0 = blockIdx.x * 64, m0 = blockIdx.y * 64;
  int tid = threadIdx.x, lane = tid & 63, wid = tid >> 6;
  f32x4 acc[4] = {};
  int sr = tid >> 2, sk = (tid & 3) * 8;
  for (int k0 = 0; k0 < K; k0 += 32) {
    short8 av = *(const short8*)(A + (size_t)(m0 + sr) * K + k0 + sk);
    *(short8*)&As[sr][sk] = av;
    short8 bv = *(const short8*)(Bw + (size_t)(n0 + sr) * K + k0 + sk);
    *(short8*)&Bs[sr][sk] = bv;
    __syncthreads();
    short8 af = *(const short8*)&As[wid * 16 + (lane & 15)][(lane >> 4) * 8];
    #pragma unroll
    for (int nt = 0; nt < 4; nt++) {
      short8 bf = *(const short8*)&Bs[nt * 16 + (lane & 15)][(lane >> 4) * 8];
      acc[nt] = __builtin_amdgcn_mfma_f32_16x16x32_bf16(af, bf, acc[nt], 0, 0, 0);
    }
    __syncthreads();
  }
  #pragma unroll
  for (int nt = 0; nt < 4; nt++) {
    int col = n0 + nt * 16 + (lane & 15);
    #pragma unroll
    for (int j = 0; j < 4; j++) {
      int row = m0 + wid * 16 + (lane >> 4) * 4 + j;
      if (!is_masked(mask, mflag, row)) C[(size_t)row * ldc + col] += acc[nt][j];
    }
  }
}

// Time-tiled depthwise conv + silu on bf16 zx.
__global__ __launch_bounds__(192) void conv_tile(const bf16_t* __restrict__ zx,
    const float* __restrict__ conv_w, const float* __restrict__ conv_b,
    bf16_t* __restrict__ xbc, int layer) {
  int tile = blockIdx.x, b = blockIdx.y, d = blockIdx.z;
  int v0 = tile * CTT;
  int tid = threadIdx.x;
  const float* cwp = conv_w + (size_t)((layer * 2 + d) * CDD) * 4;
  const float* cbp = conv_b + (layer * 2 + d) * CDD;
  float w[3][4]; float bias[3]; int ch[3];
  #pragma unroll
  for (int j = 0; j < 3; j++) {
    ch[j] = tid + 192 * j;
    bias[j] = cbp[ch[j]];
    #pragma unroll
    for (int i = 0; i < 4; i++) w[j][i] = cwp[ch[j] * 4 + i];
  }
  const bf16_t* zbase = zx + (size_t)b * SEQL * ZXT + d * ZXD + DIi;
  float win[3][3];
  #pragma unroll
  for (int k = 0; k < 3; k++) {
    int v = v0 - 3 + k;
    int t = d ? (SEQL - 1 - v) : v;
    bool ok = (v >= 0);
    #pragma unroll
    for (int j = 0; j < 3; j++)
      win[j][k] = ok ? __bfloat162float(zbase[(size_t)t * ZXT + ch[j]]) : 0.f;
  }
  for (int it = 0; it < CTT; it++) {
    int v = v0 + it;
    int t = d ? (SEQL - 1 - v) : v;
    const bf16_t* irow = zbase + (size_t)t * ZXT;
    bf16_t* orow = xbc + ((size_t)(d * RT + b * SEQL + t)) * CDD;
    #pragma unroll
    for (int j = 0; j < 3; j++) {
      float cur = __bfloat162float(irow[ch[j]]);
      float a = bias[j] + w[j][0] * win[j][0] + w[j][1] * win[j][1]
                        + w[j][2] * win[j][2] + w[j][3] * cur;
      a = a / (1.f + expf(-a));
      orow[ch[j]] = __float2bfloat16(a);
      win[j][0] = win[j][1]; win[j][1] = win[j][2]; win[j][2] = cur;
    }
  }
}

// Phase 1 (MFMA): intra-chunk Y, chunk-state S (bf16), log-gamma, P_t
__global__ __launch_bounds__(256) void chunk_p1(const bf16_t* __restrict__ xbc,
    const float* __restrict__ dtf, const float* __restrict__ dt_bias,
    const float* __restrict__ A_log,
    bf16_t* __restrict__ ybuf, bf16_t* __restrict__ Sbuf, float* __restrict__ lgbuf,
    float* __restrict__ Pbuf, int layer) {
  int c = blockIdx.x, hd = blockIdx.y, b = blockIdx.z;
  int h = hd >> 1, d = hd & 1;
  int tid = threadIdx.x, lane = tid & 63, wid = tid >> 6;
  int rb = b * SEQL;
  __shared__ __align__(16) bf16_t Bs[QC][40];    // B[s][n]
  __shared__ __align__(16) bf16_t Cs[QC][40];    // C[t][n]
  __shared__ __align__(16) bf16_t Xt[QC][72];    // X^T[p][s]
  __shared__ __align__(16) bf16_t Ms[QC][72];    // M[t][s]
  __shared__ __align__(16) bf16_t Btw[DSs][72];  // (w.B)^T[n][s]
  __shared__ float lam[QC], dts[QC], wss[QC];

  for (int i = tid; i < QC * DSs; i += 256) {
    int s = i >> 5, n = i & 31;
    const bf16_t* row = xbc + ((size_t)(d * RT + rb + torig(d, c, s))) * CDD + DIi;
    Bs[s][n] = row[n];
    Cs[s][n] = row[DSs + n];
  }
  for (int i = tid; i < QC * HDD; i += 256) {
    int s = i >> 6, p = i & 63;
    Xt[p][s] = xbc[((size_t)(d * RT + rb + torig(d, c, s))) * CDD + h * HDD + p];
  }
  if (tid < QC) {  // wave 0: dt, then inclusive scan of log-decay
    int ro = rb + torig(d, c, tid);
    size_t rr = (size_t)d * RT + ro;
    float xv = dtf[rr * NHH + h] + dt_bias[(layer * 2 + d) * NHH + h];
    float dtv = (xv > 20.f) ? xv : log1pf(expf(xv));
    float Ah = -expf(A_log[(layer * 2 + d) * NHH + h]);
    float la = dtv * Ah;
    dts[tid] = dtv;
    #pragma unroll
    for (int o = 1; o < 64; o <<= 1) { float vv = __shfl_up(la, o); if (tid >= o) la += vv; }
    lam[tid] = la;
    Pbuf[rr * NHH + h] = expf(la);
    float lq = __shfl(la, 63);
    wss[tid] = expf(lq - la) * dtv;
    if (tid == 63) lgbuf[((b * NHH + h) * 2 + d) * NCH + c] = la;  // log-gamma of chunk
  }
  __syncthreads();

  // G = C @ B^T ; M[t][s] = causal exp(lam_t-lam_s)*dt_s*G
  {
    short8 cf = *(const short8*)&Cs[wid * 16 + (lane & 15)][(lane >> 4) * 8];
    int sbase = lane & 15;
    #pragma unroll
    for (int sc = 0; sc < 4; sc++) {
      int s = sc * 16 + sbase;
      if (sc <= wid) {
        short8 bfr = *(const short8*)&Bs[s][(lane >> 4) * 8];
        f32x4 g = {};
        g = __builtin_amdgcn_mfma_f32_16x16x32_bf16(cf, bfr, g, 0, 0, 0);
        float ls = lam[s], dv = dts[s];
        #pragma unroll
        for (int j = 0; j < 4; j++) {
          int t = wid * 16 + (lane >> 4) * 4 + j;
          float m = (s <= t) ? expf(lam[t] - ls) * dv * g[j] : 0.f;
          Ms[t][s] = __float2bfloat16(m);
        }
      } else {
        #pragma unroll
        for (int j = 0; j < 4; j++) Ms[wid * 16 + (lane >> 4) * 4 + j][s] = __float2bfloat16(0.f);
      }
    }
  }
  // Btw[n][s] = wss[s] * B[s][n]
  for (int i = tid; i < DSs * QC; i += 256) {
    int n = i >> 6, s = i & 63;
    Btw[n][s] = __float2bfloat16(wss[s] * __bfloat162float(Bs[s][n]));
  }
  __syncthreads();

  // Y = M @ X : A=Ms[t][s], B=Xt[p][s]; wave wid owns t-strip
  {
    short8 ma0 = *(const short8*)&Ms[wid * 16 + (lane & 15)][(lane >> 4) * 8];
    short8 ma1 = *(const short8*)&Ms[wid * 16 + (lane & 15)][32 + (lane >> 4) * 8];
    #pragma unroll
    for (int pt = 0; pt < 4; pt++) {
      short8 xb0 = *(const short8*)&Xt[pt * 16 + (lane & 15)][(lane >> 4) * 8];
      short8 xb1 = *(const short8*)&Xt[pt * 16 + (lane & 15)][32 + (lane >> 4) * 8];
      f32x4 ya = {};
      ya = __builtin_amdgcn_mfma_f32_16x16x32_bf16(ma0, xb0, ya, 0, 0, 0);
      ya = __builtin_amdgcn_mfma_f32_16x16x32_bf16(ma1, xb1, ya, 0, 0, 0);
      int p = pt * 16 + (lane & 15);
      #pragma unroll
      for (int j = 0; j < 4; j++) {
        int t = wid * 16 + (lane >> 4) * 4 + j;
        ybuf[((size_t)(d * RT + rb + torig(d, c, t))) * DIi + h * HDD + p] = __float2bfloat16(ya[j]);
      }
    }
  }
  // S[p][n] = sum_s Xt[p][s] * Btw[n][s]; wave wid owns p-strip
  {
    short8 xa0 = *(const short8*)&Xt[wid * 16 + (lane & 15)][(lane >> 4) * 8];
    short8 xa1 = *(const short8*)&Xt[wid * 16 + (lane & 15)][32 + (lane >> 4) * 8];
    size_t base = ((size_t)((b * NHH + h) * 2 + d) * NCH + c) * 2048;
    #pragma unroll
    for (int nt = 0; nt < 2; nt++) {
      short8 bw0 = *(const short8*)&Btw[nt * 16 + (lane & 15)][(lane >> 4) * 8];
      short8 bw1 = *(const short8*)&Btw[nt * 16 + (lane & 15)][32 + (lane >> 4) * 8];
      f32x4 sa = {};
      sa = __builtin_amdgcn_mfma_f32_16x16x32_bf16(xa0, bw0, sa, 0, 0, 0);
      sa = __builtin_amdgcn_mfma_f32_16x16x32_bf16(xa1, bw1, sa, 0, 0, 0);
      int n = nt * 16 + (lane & 15);
      #pragma unroll
      for (int j = 0; j < 4; j++) {
        int p = wid * 16 + (lane >> 4) * 4 + j;
        Sbuf[base + (size_t)p * DSs + n] = __float2bfloat16(sa[j]);
      }
    }
  }
}

// Phase 2 (parallel): H_c = sum_{c'<c} exp(cum[c-1]-cum[c']) * S_{c'}
__global__ __launch_bounds__(256) void chunk_p2b(const bf16_t* __restrict__ Sbuf,
    const float* __restrict__ lgbuf, bf16_t* __restrict__ Hbuf) {
  int bhd = blockIdx.x, cb = blockIdx.y;
  int tid = threadIdx.x;
  __shared__ float W[NCH][NCH + 1];
  __shared__ float cum[NCH];
  if (tid < NCH) {
    float la = lgbuf[bhd * NCH + tid];
    #pragma unroll
    for (int o = 1; o < NCH; o <<= 1) { float v = __shfl_up(la, o); if (tid >= o) la += v; }
    cum[tid] = la;
  }
  __syncthreads();
  for (int i = tid; i < NCH * NCH; i += 256) {
    int c = i >> 5, cp = i & 31;
    W[c][cp] = (cp < c) ? expf(cum[c - 1] - cum[cp]) : 0.f;
  }
  __syncthreads();
  int j = cb * 256 + tid;
  const bf16_t* Sb = Sbuf + (size_t)bhd * NCH * 2048;
  bf16_t* Hb = Hbuf + (size_t)bhd * NCH * 2048;
  float H[NCH];
  #pragma unroll
  for (int c = 0; c < NCH; c++) H[c] = 0.f;
  for (int cp = 0; cp < NCH; cp++) {
    float s = __bfloat162float(Sb[(size_t)cp * 2048 + j]);
    #pragma unroll
    for (int c = 0; c < NCH; c++) H[c] += W[c][cp] * s;
  }
  #pragma unroll
  for (int c = 0; c < NCH; c++) Hb[(size_t)c * 2048 + j] = __float2bfloat16(H[c]);
}

// Phase 3 + gate fused: per (half-chunk, d, b) block, 512 threads (8 waves).
// Wave w computes head w: Y = intra(ybuf) + P*(C@H^T) + D*x into LDS Ys,
// then all waves gate+RMSNorm full rows from LDS and write ycat.
__global__ __launch_bounds__(512) void chunk_p3g(const bf16_t* __restrict__ xbc,
    const bf16_t* __restrict__ ybuf, const float* __restrict__ Pbuf,
    const bf16_t* __restrict__ Hbuf, const bf16_t* __restrict__ zx,
    const float* __restrict__ Dvec, const float* __restrict__ gnorm,
    bf16_t* __restrict__ ycat, int layer) {
  int cc = blockIdx.x, d = blockIdx.y, b = blockIdx.z;
  int c = cc >> 1, trow0 = (cc & 1) * 32;
  int tid = threadIdx.x, lane = tid & 63, wid = tid >> 6;
  int rb = b * SEQL;
  __shared__ __align__(16) bf16_t Cs[32][40];       // C[trel][n]
  __shared__ __align__(16) bf16_t Hs[NHH][HDD][40]; // H[h][p][n]
  __shared__ __align__(16) bf16_t Ys[32][520];      // y[trel][e]
  __shared__ float Ps[NHH][32];

  for (int i = tid; i < 32 * DSs; i += 512) {
    int s = i >> 5, n = i & 31;
    Cs[s][n] = xbc[((size_t)(d * RT + rb + torig(d, c, trow0 + s))) * CDD + DIi + DSs + n];
  }
  for (int i = tid; i < NHH * HDD * DSs; i += 512) {
    int hh = i >> 11, rem = i & 2047;
    Hs[hh][rem >> 5][rem & 31] =
        Hbuf[((size_t)((b * NHH + hh) * 2 + d) * NCH + c) * 2048 + rem];
  }
  if (tid < NHH * 32) {
    int hh = tid >> 5, t = tid & 31;
    Ps[hh][t] = Pbuf[((size_t)(d * RT + rb + torig(d, c, trow0 + t))) * NHH + hh];
  }
  __syncthreads();

  {
    int h = wid;
    float Dv = Dvec[(layer * 2 + d) * NHH + h];
    #pragma unroll
    for (int tt = 0; tt < 2; tt++) {
      short8 ca = *(const short8*)&Cs[tt * 16 + (lane & 15)][(lane >> 4) * 8];
      #pragma unroll
      for (int pp = 0; pp < 4; pp++) {
        short8 hf = *(const short8*)&Hs[h][pp * 16 + (lane & 15)][(lane >> 4) * 8];
        f32x4 a = {};
        a = __builtin_amdgcn_mfma_f32_16x16x32_bf16(ca, hf, a, 0, 0, 0);
        int p = pp * 16 + (lane & 15);
        #pragma unroll
        for (int j = 0; j < 4; j++) {
          int trel = tt * 16 + (lane >> 4) * 4 + j;
          size_t rr = (size_t)(d * RT + rb + torig(d, c, trow0 + trel));
          float xv = __bfloat162float(xbc[rr * CDD + h * HDD + p]);
          float iv = __bfloat162float(ybuf[rr * DIi + h * HDD + p]);
          Ys[trel][h * HDD + p] = __float2bfloat16(iv + Ps[h][trel] * a[j] + Dv * xv);
        }
      }
    }
  }
  __syncthreads();

  const float* gw = gnorm + (layer * 2 + d) * DIi;
  #pragma unroll
  for (int rloc = 0; rloc < 4; rloc++) {
    int trel = wid * 4 + rloc;
    int r = rb + torig(d, c, trow0 + trel);
    short8 yv8 = *(const short8*)&Ys[trel][lane * 8];
    short8 zv8 = *(const short8*)(zx + (size_t)r * ZXT + d * ZXD + lane * 8);
    float g[8]; float ss = 0.f;
    #pragma unroll
    for (int j = 0; j < 8; j++) {
      float y = bf16bits2f(yv8[j]);
      float z = bf16bits2f(zv8[j]);
      float v = y * z / (1.f + expf(-z));
      g[j] = v; ss += v * v;
    }
    #pragma unroll
    for (int o = 32; o; o >>= 1) ss += __shfl_xor(ss, o);
    float sc = rsqrtf(ss * (1.f / DIi) + EPSV);
    union { bf16_t o8[8]; uint4 u; } ov;
    #pragma unroll
    for (int j = 0; j < 8; j++)
      ov.o8[j] = __float2bfloat16(g[j] * sc * gw[lane * 8 + j]);
    *(uint4*)(ycat + (size_t)r * 1024 + d * DIi + lane * 8) = ov.u;
  }
}

extern "C" void kernel_launch(void* const* d_in, const int* in_sizes, int n_in,
                              void* d_out, int out_size, void* d_ws, size_t ws_size,
                              hipStream_t stream) {
  const float* x_in    = (const float*)d_in[0];
  const void*  maskp   = (const void*)d_in[1];
  const float* in_w    = (const float*)d_in[2];
  const float* conv_w  = (const float*)d_in[3];
  const float* conv_b  = (const float*)d_in[4];
  const float* dt_bias = (const float*)d_in[5];
  const float* A_log   = (const float*)d_in[6];
  const float* Dvec    = (const float*)d_in[7];
  const float* gnorm_w = (const float*)d_in[8];
  const float* out_w   = (const float*)d_in[9];
  const float* ln_w    = (const float*)d_in[10];
  const float* ln_b    = (const float*)d_in[11];

  char* ws = (char*)d_ws;
  size_t off = 0;
  auto alloc = [&](size_t bytes) -> void* {
    void* p = ws + off; off += (bytes + 255) & ~(size_t)255; return p;
  };
  float*  x_cur   = (float*)alloc((size_t)RT * DMm * 4);
  bf16_t* h_bf    = (bf16_t*)alloc((size_t)RT * DMm * 2);
  bf16_t* zx      = (bf16_t*)alloc((size_t)RT * ZXT * 2);
  bf16_t* xbc     = (bf16_t*)alloc((size_t)2 * RT * CDD * 2);
  float*  dtf     = (float*)alloc((size_t)2 * RT * NHH * 4);
  float*  Pbuf    = (float*)alloc((size_t)2 * RT * NHH * 4);
  bf16_t* ybuf    = (bf16_t*)alloc((size_t)2 * RT * DIi * 2);
  bf16_t* ycat    = (bf16_t*)alloc((size_t)RT * 1024 * 2);
  bf16_t* Sbuf    = (bf16_t*)alloc((size_t)64 * NCH * 2048 * 2);
  bf16_t* Hbuf    = (bf16_t*)alloc((size_t)64 * NCH * 2048 * 2);
  float*  lgbuf   = (float*)alloc((size_t)64 * NCH * 4);
  bf16_t* inw_bf  = (bf16_t*)alloc((size_t)NLAY * NPAD * DMm * 2);
  bf16_t* wcat_bf = (bf16_t*)alloc((size_t)NLAY * DMm * 1024 * 2);
  int*    mflag   = (int*)alloc(256);

  hipMemcpyAsync(x_cur, x_in, (size_t)RT * DMm * 4, hipMemcpyDeviceToDevice, stream);
  detect_mask<<<1, 256, 0, stream>>>((const unsigned char*)maskp, mflag);
  cvt_weights<<<256, 256, 0, stream>>>(in_w, out_w, inw_bf, wcat_bf);

  for (int layer = 0; layer < NLAY; layer++) {
    ln_kernel<<<RT, 64, 0, stream>>>(x_cur, h_bf, ln_w, ln_b);
    gemm_in<<<dim3(NPAD / 128, RT / 128), 256, 0, stream>>>(
        h_bf, inw_bf + (size_t)layer * NPAD * DMm, zx, dtf);
    conv_tile<<<dim3(SEQL / CTT, NB, 2), 192, 0, stream>>>(zx, conv_w, conv_b, xbc, layer);
    chunk_p1<<<dim3(NCH, 16, NB), 256, 0, stream>>>(xbc, dtf, dt_bias, A_log,
                                                    ybuf, Sbuf, lgbuf, Pbuf, layer);
    chunk_p2b<<<dim3(64, 8), 256, 0, stream>>>(Sbuf, lgbuf, Hbuf);
    chunk_p3g<<<dim3(64, 2, NB), 512, 0, stream>>>(xbc, ybuf, Pbuf, Hbuf, zx,
                                                   Dvec, gnorm_w, ycat, layer);
    gemm_out<<<dim3(DMm / 64, RT / 64), 256, 0, stream>>>(
        ycat, wcat_bf + (size_t)layer * DMm * 1024, x_cur,
        RT, DMm, 1024, DMm, maskp, mflag);
  }
  final_ln<<<RT, 64, 0, stream>>>(x_cur, maskp, mflag, ln_w, ln_b, (float*)d_out);
}